// Round 2
// baseline (4210.568 us; speedup 1.0000x reference)
//
#include <hip/hip_runtime.h>
#include <hip/hip_bf16.h>

// Problem constants (fixed by the reference)
#define D 128        // feature dim
#define NLAYER 3
#define NCH 4

#define TM 128
#define TN 128
#define KC 32

// ---------------------------------------------------------------------------
// CSR construction
// ---------------------------------------------------------------------------
__global__ void hist_kernel(const int* __restrict__ dst, int* __restrict__ deg, int E) {
    int e = blockIdx.x * 256 + threadIdx.x;
    if (e < E) atomicAdd(&deg[dst[e]], 1);
}

__global__ void scan_kernel(const int* __restrict__ deg, int* __restrict__ offs,
                            int* __restrict__ cursor, int n) {
    __shared__ int part[1024];
    int t = threadIdx.x;
    int chunk = (n + 1023) >> 10;
    int b = t * chunk;
    int e = b + chunk; if (e > n) e = n;
    int s = 0;
    for (int i = b; i < e; ++i) s += deg[i];
    part[t] = s;
    __syncthreads();
    for (int d = 1; d < 1024; d <<= 1) {
        int v = (t >= d) ? part[t - d] : 0;
        __syncthreads();
        part[t] += v;
        __syncthreads();
    }
    int run = (t == 0) ? 0 : part[t - 1];
    for (int i = b; i < e; ++i) {
        offs[i] = run; cursor[i] = run;
        run += deg[i];
    }
    if (t == 1023) offs[n] = run;   // == E
}

__global__ void fill_kernel(const int* __restrict__ src, const int* __restrict__ dst,
                            int* __restrict__ cursor, int* __restrict__ csr, int E) {
    int e = blockIdx.x * 256 + threadIdx.x;
    if (e < E) {
        int p = atomicAdd(&cursor[dst[e]], 1);
        csr[p] = src[e];
    }
}

// ---------------------------------------------------------------------------
// Aggregation: out[n] = h[n] + sum_{j in N(n)} h[src_j]; h stride = 128.
// One wave (64 lanes) per node, float2 per lane.
// ---------------------------------------------------------------------------
__global__ __launch_bounds__(256) void agg_kernel(
    const float* __restrict__ h,
    const int* __restrict__ offs, const int* __restrict__ csr,
    float* __restrict__ outb, int n)
{
    int wid = (blockIdx.x * 256 + threadIdx.x) >> 6;
    int lane = threadIdx.x & 63;
    if (wid >= n) return;
    float2 acc = *((const float2*)(h + (size_t)wid * D) + lane);
    int b = offs[wid], e = offs[wid + 1];
    int j = b;
    for (; j + 2 <= e; j += 2) {
        int s0 = csr[j], s1 = csr[j + 1];
        float2 v0 = *((const float2*)(h + (size_t)s0 * D) + lane);
        float2 v1 = *((const float2*)(h + (size_t)s1 * D) + lane);
        acc.x += v0.x + v1.x;
        acc.y += v0.y + v1.y;
    }
    if (j < e) {
        int s0 = csr[j];
        float2 v0 = *((const float2*)(h + (size_t)s0 * D) + lane);
        acc.x += v0.x; acc.y += v0.y;
    }
    *((float2*)(outb + (size_t)wid * D) + lane) = acc;
}

// ---------------------------------------------------------------------------
// Conv linear: 128x128, bias+relu, in-place safe (Out==A, gridDim.y==1):
// each block stages only its own 128 rows (fully consumed before its writes).
// ---------------------------------------------------------------------------
__global__ __launch_bounds__(256, 2) void gemm128_relu(
    const float* __restrict__ A,
    const float* __restrict__ W,      // [128,128]
    const float* __restrict__ bias,   // [128]
    float* __restrict__ Out,
    int nrows)
{
    __shared__ __align__(16) float Al[TM][KC + 4];
    __shared__ __align__(16) float Wl[KC][TN];
    const int t = threadIdx.x;
    const int rowbase = blockIdx.x * TM;
    const int tr = t >> 4;    // 0..15
    const int tc = t & 15;    // 0..15

    float acc[8][8];
#pragma unroll
    for (int r = 0; r < 8; ++r)
#pragma unroll
        for (int j = 0; j < 8; ++j) acc[r][j] = 0.f;

    for (int kc = 0; kc < 128; kc += KC) {
#pragma unroll
        for (int pass = 0; pass < 4; ++pass) {
            int r = (t >> 3) + pass * 32;
            int kq = (t & 7) * 4;
            int grow = rowbase + r;
            float4 v = make_float4(0.f, 0.f, 0.f, 0.f);
            if (grow < nrows) v = *(const float4*)(A + (size_t)grow * D + kc + kq);
            *(float4*)&Al[r][kq] = v;
        }
#pragma unroll
        for (int pass = 0; pass < 4; ++pass) {
            int k = (t >> 5) + pass * 8;
            int cq = (t & 31) * 4;
            *(float4*)&Wl[k][cq] = *(const float4*)(W + (size_t)(kc + k) * D + cq);
        }
        __syncthreads();
#pragma unroll
        for (int k4 = 0; k4 < KC; k4 += 4) {
            float4 a4[8];
#pragma unroll
            for (int r = 0; r < 8; ++r) a4[r] = *(const float4*)&Al[tr * 8 + r][k4];
#pragma unroll
            for (int kk = 0; kk < 4; ++kk) {
                float4 w0 = *(const float4*)&Wl[k4 + kk][tc * 4];
                float4 w1 = *(const float4*)&Wl[k4 + kk][64 + tc * 4];
#pragma unroll
                for (int r = 0; r < 8; ++r) {
                    float av = ((const float*)&a4[r])[kk];
                    acc[r][0] += av * w0.x; acc[r][1] += av * w0.y;
                    acc[r][2] += av * w0.z; acc[r][3] += av * w0.w;
                    acc[r][4] += av * w1.x; acc[r][5] += av * w1.y;
                    acc[r][6] += av * w1.z; acc[r][7] += av * w1.w;
                }
            }
        }
        __syncthreads();
    }

    float4 b0 = *(const float4*)(bias + tc * 4);
    float4 b1 = *(const float4*)(bias + 64 + tc * 4);
#pragma unroll
    for (int r = 0; r < 8; ++r) {
        int grow = rowbase + tr * 8 + r;
        if (grow < nrows) {
            float4 o0, o1;
            o0.x = fmaxf(acc[r][0] + b0.x, 0.f);
            o0.y = fmaxf(acc[r][1] + b0.y, 0.f);
            o0.z = fmaxf(acc[r][2] + b0.z, 0.f);
            o0.w = fmaxf(acc[r][3] + b0.w, 0.f);
            o1.x = fmaxf(acc[r][4] + b1.x, 0.f);
            o1.y = fmaxf(acc[r][5] + b1.y, 0.f);
            o1.z = fmaxf(acc[r][6] + b1.z, 0.f);
            o1.w = fmaxf(acc[r][7] + b1.w, 0.f);
            *(float4*)(Out + (size_t)grow * D + tc * 4) = o0;
            *(float4*)(Out + (size_t)grow * D + 64 + tc * 4) = o1;
        }
    }
}

// ---------------------------------------------------------------------------
// Channel layer 1: virtual concat [x|h1|h2|h3] (each stride 128) @ W1 [512,256]
// + bias + relu -> t1 chunk [R,256]. Each KC=32 chunk lies in one slice.
// ---------------------------------------------------------------------------
__global__ __launch_bounds__(256, 2) void gemm_cat_relu(
    const float* __restrict__ A0, const float* __restrict__ A1,
    const float* __restrict__ A2, const float* __restrict__ A3,
    const float* __restrict__ W,      // [512,256]
    const float* __restrict__ bias,   // [256]
    float* __restrict__ Out,          // chunk base, ld=256
    int r0, int N)
{
    __shared__ __align__(16) float Al[TM][KC + 4];
    __shared__ __align__(16) float Wl[KC][TN];
    const int t = threadIdx.x;
    const int lrowbase = blockIdx.x * TM;
    const int colbase = blockIdx.y * TN;   // 0 or 128
    const int tr = t >> 4;
    const int tc = t & 15;
    const float* As[4] = {A0, A1, A2, A3};

    float acc[8][8];
#pragma unroll
    for (int r = 0; r < 8; ++r)
#pragma unroll
        for (int j = 0; j < 8; ++j) acc[r][j] = 0.f;

    for (int kc = 0; kc < 512; kc += KC) {
        const float* Ab = As[kc >> 7];
        const int within = kc & 127;
#pragma unroll
        for (int pass = 0; pass < 4; ++pass) {
            int r = (t >> 3) + pass * 32;
            int kq = (t & 7) * 4;
            int grow = r0 + lrowbase + r;
            float4 v = make_float4(0.f, 0.f, 0.f, 0.f);
            if (grow < N) v = *(const float4*)(Ab + (size_t)grow * D + within + kq);
            *(float4*)&Al[r][kq] = v;
        }
#pragma unroll
        for (int pass = 0; pass < 4; ++pass) {
            int k = (t >> 5) + pass * 8;
            int cq = (t & 31) * 4;
            *(float4*)&Wl[k][cq] = *(const float4*)(W + (size_t)(kc + k) * 256 + colbase + cq);
        }
        __syncthreads();
#pragma unroll
        for (int k4 = 0; k4 < KC; k4 += 4) {
            float4 a4[8];
#pragma unroll
            for (int r = 0; r < 8; ++r) a4[r] = *(const float4*)&Al[tr * 8 + r][k4];
#pragma unroll
            for (int kk = 0; kk < 4; ++kk) {
                float4 w0 = *(const float4*)&Wl[k4 + kk][tc * 4];
                float4 w1 = *(const float4*)&Wl[k4 + kk][64 + tc * 4];
#pragma unroll
                for (int r = 0; r < 8; ++r) {
                    float av = ((const float*)&a4[r])[kk];
                    acc[r][0] += av * w0.x; acc[r][1] += av * w0.y;
                    acc[r][2] += av * w0.z; acc[r][3] += av * w0.w;
                    acc[r][4] += av * w1.x; acc[r][5] += av * w1.y;
                    acc[r][6] += av * w1.z; acc[r][7] += av * w1.w;
                }
            }
        }
        __syncthreads();
    }

    float4 b0 = *(const float4*)(bias + colbase + tc * 4);
    float4 b1 = *(const float4*)(bias + colbase + 64 + tc * 4);
#pragma unroll
    for (int r = 0; r < 8; ++r) {
        int lrow = lrowbase + tr * 8 + r;
        if (r0 + lrow < N) {
            float4 o0, o1;
            o0.x = fmaxf(acc[r][0] + b0.x, 0.f);
            o0.y = fmaxf(acc[r][1] + b0.y, 0.f);
            o0.z = fmaxf(acc[r][2] + b0.z, 0.f);
            o0.w = fmaxf(acc[r][3] + b0.w, 0.f);
            o1.x = fmaxf(acc[r][4] + b1.x, 0.f);
            o1.y = fmaxf(acc[r][5] + b1.y, 0.f);
            o1.z = fmaxf(acc[r][6] + b1.z, 0.f);
            o1.w = fmaxf(acc[r][7] + b1.w, 0.f);
            *(float4*)(Out + (size_t)lrow * 256 + colbase + tc * 4) = o0;
            *(float4*)(Out + (size_t)lrow * 256 + colbase + 64 + tc * 4) = o1;
        }
    }
}

// ---------------------------------------------------------------------------
// Fused channel layers 2+3 (per channel c):
//   h2 = relu(t1 @ W2 + b2); out[n][c] = relu(h2[n] . w3 + b3)
// Block: 64 rows x 256 cols; thread 8x8.
// ---------------------------------------------------------------------------
__global__ __launch_bounds__(256, 2) void chan23_kernel(
    const float* __restrict__ A,      // t1 chunk [rows,256]
    const float* __restrict__ W2,     // [256,256]
    const float* __restrict__ b2,     // [256]
    const float* __restrict__ w3,     // [256]
    const float* __restrict__ b3,     // [1]
    float* __restrict__ out,          // out + r0*4
    int rows, int c)
{
    __shared__ __align__(16) float Al[64][KC + 4];
    __shared__ __align__(16) float Wl[KC][256];
    __shared__ float red[64][33];
    const int t = threadIdx.x;
    const int rowbase = blockIdx.x * 64;
    const int tr = t >> 5;    // 0..7
    const int tc = t & 31;    // 0..31

    float acc[8][8];
#pragma unroll
    for (int r = 0; r < 8; ++r)
#pragma unroll
        for (int j = 0; j < 8; ++j) acc[r][j] = 0.f;

    for (int kc = 0; kc < 256; kc += KC) {
#pragma unroll
        for (int pass = 0; pass < 2; ++pass) {
            int r = (t >> 3) + pass * 32;
            int kq = (t & 7) * 4;
            int lrow = rowbase + r;
            float4 v = make_float4(0.f, 0.f, 0.f, 0.f);
            if (lrow < rows) v = *(const float4*)(A + (size_t)lrow * 256 + kc + kq);
            *(float4*)&Al[r][kq] = v;
        }
#pragma unroll
        for (int pass = 0; pass < 8; ++pass) {
            int k = (t >> 6) + pass * 4;
            int cq = (t & 63) * 4;
            *(float4*)&Wl[k][cq] = *(const float4*)(W2 + (size_t)(kc + k) * 256 + cq);
        }
        __syncthreads();
#pragma unroll
        for (int k4 = 0; k4 < KC; k4 += 4) {
            float4 a4[8];
#pragma unroll
            for (int r = 0; r < 8; ++r) a4[r] = *(const float4*)&Al[tr * 8 + r][k4];
#pragma unroll
            for (int kk = 0; kk < 4; ++kk) {
                float4 w0 = *(const float4*)&Wl[k4 + kk][tc * 4];
                float4 w1 = *(const float4*)&Wl[k4 + kk][128 + tc * 4];
#pragma unroll
                for (int r = 0; r < 8; ++r) {
                    float av = ((const float*)&a4[r])[kk];
                    acc[r][0] += av * w0.x; acc[r][1] += av * w0.y;
                    acc[r][2] += av * w0.z; acc[r][3] += av * w0.w;
                    acc[r][4] += av * w1.x; acc[r][5] += av * w1.y;
                    acc[r][6] += av * w1.z; acc[r][7] += av * w1.w;
                }
            }
        }
        __syncthreads();
    }

    float4 b20 = *(const float4*)(b2 + tc * 4);
    float4 b21 = *(const float4*)(b2 + 128 + tc * 4);
    float4 w30 = *(const float4*)(w3 + tc * 4);
    float4 w31 = *(const float4*)(w3 + 128 + tc * 4);
#pragma unroll
    for (int r = 0; r < 8; ++r) {
        float h0 = fmaxf(acc[r][0] + b20.x, 0.f);
        float h1 = fmaxf(acc[r][1] + b20.y, 0.f);
        float h2 = fmaxf(acc[r][2] + b20.z, 0.f);
        float h3 = fmaxf(acc[r][3] + b20.w, 0.f);
        float h4 = fmaxf(acc[r][4] + b21.x, 0.f);
        float h5 = fmaxf(acc[r][5] + b21.y, 0.f);
        float h6 = fmaxf(acc[r][6] + b21.z, 0.f);
        float h7 = fmaxf(acc[r][7] + b21.w, 0.f);
        float part = h0 * w30.x + h1 * w30.y + h2 * w30.z + h3 * w30.w
                   + h4 * w31.x + h5 * w31.y + h6 * w31.z + h7 * w31.w;
        red[tr * 8 + r][tc] = part;
    }
    __syncthreads();
    if (t < 64) {
        int lrow = rowbase + t;
        if (lrow < rows) {
            float s = 0.f;
#pragma unroll
            for (int i = 0; i < 32; ++i) s += red[t][i];
            out[(size_t)lrow * NCH + c] = fmaxf(s + b3[0], 0.f);
        }
    }
}

// ---------------------------------------------------------------------------
// Launch
// ---------------------------------------------------------------------------
extern "C" void kernel_launch(void* const* d_in, const int* in_sizes, int n_in,
                              void* d_out, int out_size, void* d_ws, size_t ws_size,
                              hipStream_t stream) {
    const float* x        = (const float*)d_in[0];
    const int*   eidx     = (const int*)d_in[1];
    const float* convW    = (const float*)d_in[2];
    const float* convB    = (const float*)d_in[3];
    const float* chanW1   = (const float*)d_in[4];
    const float* chanB1   = (const float*)d_in[5];
    const float* chanW2   = (const float*)d_in[6];
    const float* chanB2   = (const float*)d_in[7];
    const float* chanW3   = (const float*)d_in[8];
    const float* chanB3   = (const float*)d_in[9];
    float* out = (float*)d_out;

    const int N = in_sizes[0] / D;      // 100000
    const int E = in_sizes[1] / 2;      // 1600000
    const int* srcp = eidx;
    const int* dstp = eidx + E;

    // workspace carve-up (aligned to 256B), minimal footprint:
    //   h0,h1,h2 : 3 * N*128*4 = 153.6 MB   (layer outputs, live to the end)
    //   deg/offs/cursor : ~1.2 MB
    //   remaining region shared by csr (GIN phase) and t1 chunk (channel phase)
    char* w = (char*)d_ws;
    auto take = [&](size_t bytes) {
        char* p = w;
        w += (bytes + 255) & ~(size_t)255;
        return p;
    };
    float* h0     = (float*)take((size_t)N * D * 4);
    float* h1     = (float*)take((size_t)N * D * 4);
    float* h2     = (float*)take((size_t)N * D * 4);
    int*   deg    = (int*)take((size_t)N * 4);
    int*   offs   = (int*)take((size_t)(N + 1) * 4);
    int*   cursor = (int*)take((size_t)N * 4);

    size_t used = (size_t)(w - (char*)d_ws);
    if (used > ws_size) return;                       // clean diagnostic failure
    size_t rem = ws_size - used;
    size_t need_csr = (size_t)E * 4;
    size_t need_t1min = (size_t)128 * 256 * 4;
    if (rem < need_csr || rem < need_t1min) return;   // clean diagnostic failure

    int*   csr = (int*)w;        // live during GIN phase only
    float* t1  = (float*)w;      // live during channel phase only (overlaps csr)
    long t1rows = (long)(rem / (256 * 4));
    int R = (int)((t1rows / 128) * 128);
    const int Nup = ((N + 127) / 128) * 128;
    if (R > Nup) R = Nup;

    // --- CSR build ---
    hipMemsetAsync(deg, 0, (size_t)N * 4, stream);
    hist_kernel<<<(E + 255) / 256, 256, 0, stream>>>(dstp, deg, E);
    scan_kernel<<<1, 1024, 0, stream>>>(deg, offs, cursor, N);
    fill_kernel<<<(E + 255) / 256, 256, 0, stream>>>(srcp, dstp, cursor, csr, E);

    const int rowtiles = (N + TM - 1) / TM;          // 782
    const int aggblocks = (N * 64 + 255) / 256;      // 25000

    // --- GIN layers: agg into h[l], then 3 conv linears in-place on h[l] ---
    float* hbuf[NLAYER] = {h0, h1, h2};
    const float* prev = x;
    for (int l = 0; l < NLAYER; ++l) {
        agg_kernel<<<aggblocks, 256, 0, stream>>>(prev, offs, csr, hbuf[l], N);
        for (int k = 0; k < 3; ++k) {
            const float* Wk = convW + ((size_t)(l * 3 + k)) * D * D;
            const float* Bk = convB + ((size_t)(l * 3 + k)) * D;
            gemm128_relu<<<rowtiles, 256, 0, stream>>>(hbuf[l], Wk, Bk, hbuf[l], N);
        }
        prev = hbuf[l];
    }

    // --- channel MLPs, chunked over rows to fit t1 in remaining workspace ---
    for (int c = 0; c < NCH; ++c) {
        for (int r0 = 0; r0 < N; r0 += R) {
            int rows = N - r0; if (rows > R) rows = R;
            int rt = (rows + TM - 1) / TM;
            gemm_cat_relu<<<dim3(rt, 2), 256, 0, stream>>>(
                x, h0, h1, h2,
                chanW1 + (size_t)c * 512 * 256,
                chanB1 + (size_t)c * 256,
                t1, r0, N);
            chan23_kernel<<<(rows + 63) / 64, 256, 0, stream>>>(
                t1,
                chanW2 + (size_t)c * 256 * 256,
                chanB2 + (size_t)c * 256,
                chanW3 + (size_t)c * 256,
                chanB3 + c,
                out + (size_t)r0 * NCH, rows, c);
        }
    }
}

// Round 3
// 2036.693 us; speedup vs baseline: 2.0674x; 2.0674x over previous
//
#include <hip/hip_runtime.h>
#include <hip/hip_bf16.h>

// Problem constants (fixed by the reference)
#define D 128        // feature dim
#define NLAYER 3
#define NCH 4

#define TM 128
#define TN 128
#define KC 32

typedef __attribute__((ext_vector_type(8))) short short8;
typedef __attribute__((ext_vector_type(4))) float f32x4;

__device__ __forceinline__ ushort f2bf(float f) {
    unsigned int u = __builtin_bit_cast(unsigned int, f);
    u += 0x7fffu + ((u >> 16) & 1u);     // RNE
    return (ushort)(u >> 16);
}

// ---------------------------------------------------------------------------
// CSR construction
// ---------------------------------------------------------------------------
__global__ void hist_kernel(const int* __restrict__ dst, int* __restrict__ deg, int E) {
    int e = blockIdx.x * 256 + threadIdx.x;
    if (e < E) atomicAdd(&deg[dst[e]], 1);
}

__global__ void scan_kernel(const int* __restrict__ deg, int* __restrict__ offs,
                            int* __restrict__ cursor, int n) {
    __shared__ int part[1024];
    int t = threadIdx.x;
    int chunk = (n + 1023) >> 10;
    int b = t * chunk;
    int e = b + chunk; if (e > n) e = n;
    int s = 0;
    for (int i = b; i < e; ++i) s += deg[i];
    part[t] = s;
    __syncthreads();
    for (int d = 1; d < 1024; d <<= 1) {
        int v = (t >= d) ? part[t - d] : 0;
        __syncthreads();
        part[t] += v;
        __syncthreads();
    }
    int run = (t == 0) ? 0 : part[t - 1];
    for (int i = b; i < e; ++i) {
        offs[i] = run; cursor[i] = run;
        run += deg[i];
    }
    if (t == 1023) offs[n] = run;   // == E
}

__global__ void fill_kernel(const int* __restrict__ src, const int* __restrict__ dst,
                            int* __restrict__ cursor, int* __restrict__ csr, int E) {
    int e = blockIdx.x * 256 + threadIdx.x;
    if (e < E) {
        int p = atomicAdd(&cursor[dst[e]], 1);
        csr[p] = src[e];
    }
}

// ---------------------------------------------------------------------------
// Aggregation: out[n] = h[n] + sum_{j in N(n)} h[src_j]; h stride = 128. fp32.
// ---------------------------------------------------------------------------
__global__ __launch_bounds__(256) void agg_kernel(
    const float* __restrict__ h,
    const int* __restrict__ offs, const int* __restrict__ csr,
    float* __restrict__ outb, int n)
{
    int wid = (blockIdx.x * 256 + threadIdx.x) >> 6;
    int lane = threadIdx.x & 63;
    if (wid >= n) return;
    float2 acc = *((const float2*)(h + (size_t)wid * D) + lane);
    int b = offs[wid], e = offs[wid + 1];
    int j = b;
    for (; j + 2 <= e; j += 2) {
        int s0 = csr[j], s1 = csr[j + 1];
        float2 v0 = *((const float2*)(h + (size_t)s0 * D) + lane);
        float2 v1 = *((const float2*)(h + (size_t)s1 * D) + lane);
        acc.x += v0.x + v1.x;
        acc.y += v0.y + v1.y;
    }
    if (j < e) {
        int s0 = csr[j];
        float2 v0 = *((const float2*)(h + (size_t)s0 * D) + lane);
        acc.x += v0.x; acc.y += v0.y;
    }
    *((float2*)(outb + (size_t)wid * D) + lane) = acc;
}

// ---------------------------------------------------------------------------
// Conv linear: 128x128 fp32, bias+relu, in-place safe (unchanged from R2).
// ---------------------------------------------------------------------------
__global__ __launch_bounds__(256, 2) void gemm128_relu(
    const float* __restrict__ A,
    const float* __restrict__ W,
    const float* __restrict__ bias,
    float* __restrict__ Out,
    int nrows)
{
    __shared__ __align__(16) float Al[TM][KC + 4];
    __shared__ __align__(16) float Wl[KC][TN];
    const int t = threadIdx.x;
    const int rowbase = blockIdx.x * TM;
    const int tr = t >> 4;
    const int tc = t & 15;

    float acc[8][8];
#pragma unroll
    for (int r = 0; r < 8; ++r)
#pragma unroll
        for (int j = 0; j < 8; ++j) acc[r][j] = 0.f;

    for (int kc = 0; kc < 128; kc += KC) {
#pragma unroll
        for (int pass = 0; pass < 4; ++pass) {
            int r = (t >> 3) + pass * 32;
            int kq = (t & 7) * 4;
            int grow = rowbase + r;
            float4 v = make_float4(0.f, 0.f, 0.f, 0.f);
            if (grow < nrows) v = *(const float4*)(A + (size_t)grow * D + kc + kq);
            *(float4*)&Al[r][kq] = v;
        }
#pragma unroll
        for (int pass = 0; pass < 4; ++pass) {
            int k = (t >> 5) + pass * 8;
            int cq = (t & 31) * 4;
            *(float4*)&Wl[k][cq] = *(const float4*)(W + (size_t)(kc + k) * D + cq);
        }
        __syncthreads();
#pragma unroll
        for (int k4 = 0; k4 < KC; k4 += 4) {
            float4 a4[8];
#pragma unroll
            for (int r = 0; r < 8; ++r) a4[r] = *(const float4*)&Al[tr * 8 + r][k4];
#pragma unroll
            for (int kk = 0; kk < 4; ++kk) {
                float4 w0 = *(const float4*)&Wl[k4 + kk][tc * 4];
                float4 w1 = *(const float4*)&Wl[k4 + kk][64 + tc * 4];
#pragma unroll
                for (int r = 0; r < 8; ++r) {
                    float av = ((const float*)&a4[r])[kk];
                    acc[r][0] += av * w0.x; acc[r][1] += av * w0.y;
                    acc[r][2] += av * w0.z; acc[r][3] += av * w0.w;
                    acc[r][4] += av * w1.x; acc[r][5] += av * w1.y;
                    acc[r][6] += av * w1.z; acc[r][7] += av * w1.w;
                }
            }
        }
        __syncthreads();
    }

    float4 b0 = *(const float4*)(bias + tc * 4);
    float4 b1 = *(const float4*)(bias + 64 + tc * 4);
#pragma unroll
    for (int r = 0; r < 8; ++r) {
        int grow = rowbase + tr * 8 + r;
        if (grow < nrows) {
            float4 o0, o1;
            o0.x = fmaxf(acc[r][0] + b0.x, 0.f);
            o0.y = fmaxf(acc[r][1] + b0.y, 0.f);
            o0.z = fmaxf(acc[r][2] + b0.z, 0.f);
            o0.w = fmaxf(acc[r][3] + b0.w, 0.f);
            o1.x = fmaxf(acc[r][4] + b1.x, 0.f);
            o1.y = fmaxf(acc[r][5] + b1.y, 0.f);
            o1.z = fmaxf(acc[r][6] + b1.z, 0.f);
            o1.w = fmaxf(acc[r][7] + b1.w, 0.f);
            *(float4*)(Out + (size_t)grow * D + tc * 4) = o0;
            *(float4*)(Out + (size_t)grow * D + 64 + tc * 4) = o1;
        }
    }
}

// ---------------------------------------------------------------------------
// Weight transpose + fp32->bf16: Wt[c][n][k] = bf16(W[c][k][n])
// grid (K/32, Ncols/32, C), 256 threads
// ---------------------------------------------------------------------------
__global__ void cvtW_kernel(const float* __restrict__ W, ushort* __restrict__ Wt,
                            int K, int Ncols) {
    __shared__ float tile[32][33];
    int c = blockIdx.z;
    int k0 = blockIdx.x * 32, n0 = blockIdx.y * 32;
    const float* Wc = W + (size_t)c * K * Ncols;
    ushort* Wtc = Wt + (size_t)c * K * Ncols;
    int tx = threadIdx.x & 31, ty = threadIdx.x >> 5;   // ty 0..7
#pragma unroll
    for (int i = 0; i < 4; ++i) {
        int k = k0 + ty + i * 8;
        tile[ty + i * 8][tx] = Wc[(size_t)k * Ncols + n0 + tx];
    }
    __syncthreads();
#pragma unroll
    for (int i = 0; i < 4; ++i) {
        int n = n0 + ty + i * 8;
        Wtc[(size_t)n * K + k0 + tx] = f2bf(tile[tx][ty + i * 8]);
    }
}

// ---------------------------------------------------------------------------
// Channel layer 1, bf16 MFMA: T1[r][col] = relu( xcat[r] @ W1 + b1 ), bf16 out.
// A = virtual concat {x,h0,h1,h2} fp32 (cvt on the fly), B = Wt [256][512] bf16
// (pre-transposed, k-contiguous). Tile 128x128, 4 waves of 64x64, BK=64.
// LDS: XOR-swizzled 16B granules -> <=2-way bank conflicts on ds_read_b128.
// ---------------------------------------------------------------------------
__global__ __launch_bounds__(256) void chan_l1_mfma(
    const float* __restrict__ A0, const float* __restrict__ A1,
    const float* __restrict__ A2, const float* __restrict__ A3,
    const ushort* __restrict__ Wt,     // [256][512] bf16, this channel
    const float* __restrict__ b1,      // [256]
    ushort* __restrict__ T1,           // [rows][256] bf16 (chunk-local)
    int r0, int rows, int N)
{
    __shared__ __align__(16) ushort As[128 * 64];   // 16 KB
    __shared__ __align__(16) ushort Bs[128 * 64];   // 16 KB
    const int t = threadIdx.x;
    const int w = t >> 6, lane = t & 63;
    const int quad = lane >> 4, c15 = lane & 15;
    const int wr = w >> 1, wc = w & 1;
    const int rowbase = blockIdx.x * 128;
    const int colbase = blockIdx.y * 128;
    const float* Asrc[4] = {A0, A1, A2, A3};

    f32x4 acc[4][4];
#pragma unroll
    for (int i = 0; i < 4; ++i)
#pragma unroll
        for (int j = 0; j < 4; ++j)
#pragma unroll
            for (int r = 0; r < 4; ++r) acc[i][j][r] = 0.f;

    for (int kc = 0; kc < 512; kc += 64) {
        const float* Ab = Asrc[kc >> 7];
        const int within = kc & 127;
        // --- A stage: load fp32, cvt bf16, swizzled ds_write_b128 ---
#pragma unroll
        for (int i = 0; i < 4; ++i) {
            int lin = i * 256 + t;              // granule 0..1023
            int row = lin >> 3, slot = lin & 7;
            int grow = r0 + rowbase + row;
            if (grow >= N) grow = r0;
            const float* gp = Ab + (size_t)grow * D + within + slot * 8;
            float4 v0 = *(const float4*)gp;
            float4 v1 = *(const float4*)(gp + 4);
            short8 pk;
            pk[0] = (short)f2bf(v0.x); pk[1] = (short)f2bf(v0.y);
            pk[2] = (short)f2bf(v0.z); pk[3] = (short)f2bf(v0.w);
            pk[4] = (short)f2bf(v1.x); pk[5] = (short)f2bf(v1.y);
            pk[6] = (short)f2bf(v1.z); pk[7] = (short)f2bf(v1.w);
            *(short8*)&As[row * 64 + (slot ^ (row & 7)) * 8] = pk;
        }
        // --- B stage: global_load_lds 16B, swizzled via source permute ---
#pragma unroll
        for (int i = 0; i < 4; ++i) {
            int lin = (i * 4 + w) * 64 + lane;  // granule 0..1023
            int n = lin >> 3, slot = lin & 7;
            int g = slot ^ (n & 7);
            const ushort* gp = Wt + (size_t)(colbase + n) * 512 + kc + g * 8;
            __builtin_amdgcn_global_load_lds(
                (const __attribute__((address_space(1))) void*)gp,
                (__attribute__((address_space(3))) void*)&Bs[(i * 4 + w) * 512],
                16, 0, 0);
        }
        __syncthreads();
#pragma unroll
        for (int ks = 0; ks < 2; ++ks) {
            const int K8 = ks * 4;
            short8 af[4], bf[4];
#pragma unroll
            for (int tr = 0; tr < 4; ++tr) {
                int r = wr * 64 + tr * 16 + c15;
                af[tr] = *(const short8*)&As[r * 64 + (((K8 + quad) ^ (r & 7)) * 8)];
            }
#pragma unroll
            for (int tc = 0; tc < 4; ++tc) {
                int n = wc * 64 + tc * 16 + c15;
                bf[tc] = *(const short8*)&Bs[n * 64 + (((K8 + quad) ^ (n & 7)) * 8)];
            }
#pragma unroll
            for (int tr = 0; tr < 4; ++tr)
#pragma unroll
                for (int tc = 0; tc < 4; ++tc)
                    acc[tr][tc] = __builtin_amdgcn_mfma_f32_16x16x32_bf16(
                        af[tr], bf[tc], acc[tr][tc], 0, 0, 0);
        }
        __syncthreads();
    }

    // epilogue: bias + relu + bf16 store to T1
#pragma unroll
    for (int tc = 0; tc < 4; ++tc) {
        int col = colbase + wc * 64 + tc * 16 + c15;
        float bias = b1[col];
#pragma unroll
        for (int tr = 0; tr < 4; ++tr)
#pragma unroll
            for (int rg = 0; rg < 4; ++rg) {
                int lrow = rowbase + wr * 64 + tr * 16 + quad * 4 + rg;
                if (lrow < rows)
                    T1[(size_t)lrow * 256 + col] = f2bf(fmaxf(acc[tr][tc][rg] + bias, 0.f));
            }
    }
}

// ---------------------------------------------------------------------------
// Channel layers 2+3 fused, bf16 MFMA:
//   h2 = relu(T1 @ W2 + b2); out[r][c] = relu(h2 . w3 + b3)
// Block 64 rows x 256 cols; 4 waves each own 64 cols (4x4 mfma tiles). BK=64.
// ---------------------------------------------------------------------------
__global__ __launch_bounds__(256) void chan_l23_mfma(
    const ushort* __restrict__ T1,     // [rows][256] bf16
    const ushort* __restrict__ Wt2,    // [256][256] bf16 (n-major)
    const float* __restrict__ b2,      // [256]
    const float* __restrict__ w3,      // [256]
    const float* __restrict__ b3,      // [1]
    float* __restrict__ out,           // [N,4]
    int r0, int rows, int c)
{
    __shared__ __align__(16) ushort As[64 * 64];    //  8 KB
    __shared__ __align__(16) ushort Bs[256 * 64];   // 32 KB
    __shared__ float red[64][4];
    const int t = threadIdx.x;
    const int w = t >> 6, lane = t & 63;
    const int quad = lane >> 4, c15 = lane & 15;
    const int rowbase = blockIdx.x * 64;

    f32x4 acc[4][4];
#pragma unroll
    for (int i = 0; i < 4; ++i)
#pragma unroll
        for (int j = 0; j < 4; ++j)
#pragma unroll
            for (int r = 0; r < 4; ++r) acc[i][j][r] = 0.f;

    for (int kc = 0; kc < 256; kc += 64) {
        // --- A stage: 512 granules via global_load_lds ---
#pragma unroll
        for (int i = 0; i < 2; ++i) {
            int lin = (i * 4 + w) * 64 + lane;
            int row = lin >> 3, slot = lin & 7;
            int g = slot ^ (row & 7);
            int lrow = rowbase + row;
            if (lrow >= rows) lrow = 0;
            const ushort* gp = T1 + (size_t)lrow * 256 + kc + g * 8;
            __builtin_amdgcn_global_load_lds(
                (const __attribute__((address_space(1))) void*)gp,
                (__attribute__((address_space(3))) void*)&As[(i * 4 + w) * 512],
                16, 0, 0);
        }
        // --- B stage: 2048 granules ---
#pragma unroll
        for (int i = 0; i < 8; ++i) {
            int lin = (i * 4 + w) * 64 + lane;
            int n = lin >> 3, slot = lin & 7;
            int g = slot ^ (n & 7);
            const ushort* gp = Wt2 + (size_t)n * 256 + kc + g * 8;
            __builtin_amdgcn_global_load_lds(
                (const __attribute__((address_space(1))) void*)gp,
                (__attribute__((address_space(3))) void*)&Bs[(i * 4 + w) * 512],
                16, 0, 0);
        }
        __syncthreads();
#pragma unroll
        for (int ks = 0; ks < 2; ++ks) {
            const int K8 = ks * 4;
            short8 af[4], bf[4];
#pragma unroll
            for (int tr = 0; tr < 4; ++tr) {
                int r = tr * 16 + c15;
                af[tr] = *(const short8*)&As[r * 64 + (((K8 + quad) ^ (r & 7)) * 8)];
            }
#pragma unroll
            for (int tc = 0; tc < 4; ++tc) {
                int n = w * 64 + tc * 16 + c15;
                bf[tc] = *(const short8*)&Bs[n * 64 + (((K8 + quad) ^ (n & 7)) * 8)];
            }
#pragma unroll
            for (int tr = 0; tr < 4; ++tr)
#pragma unroll
                for (int tc = 0; tc < 4; ++tc)
                    acc[tr][tc] = __builtin_amdgcn_mfma_f32_16x16x32_bf16(
                        af[tr], bf[tc], acc[tr][tc], 0, 0, 0);
        }
        __syncthreads();
    }

    // epilogue: relu(acc+b2) dot w3, reduce over the 16 col-lanes + 4 col-tiles
    float b2v[4], w3v[4];
#pragma unroll
    for (int tc = 0; tc < 4; ++tc) {
        int col = w * 64 + tc * 16 + c15;
        b2v[tc] = b2[col];
        w3v[tc] = w3[col];
    }
#pragma unroll
    for (int tr = 0; tr < 4; ++tr)
#pragma unroll
        for (int rg = 0; rg < 4; ++rg) {
            float p = 0.f;
#pragma unroll
            for (int tc = 0; tc < 4; ++tc)
                p += fmaxf(acc[tr][tc][rg] + b2v[tc], 0.f) * w3v[tc];
            p += __shfl_xor(p, 1);
            p += __shfl_xor(p, 2);
            p += __shfl_xor(p, 4);
            p += __shfl_xor(p, 8);
            if (c15 == 0) red[tr * 16 + quad * 4 + rg][w] = p;
        }
    __syncthreads();
    if (t < 64) {
        int lrow = rowbase + t;
        if (lrow < rows) {
            float s = red[t][0] + red[t][1] + red[t][2] + red[t][3] + b3[0];
            out[(size_t)(r0 + lrow) * NCH + c] = fmaxf(s, 0.f);
        }
    }
}

// ---------------------------------------------------------------------------
// Launch
// ---------------------------------------------------------------------------
extern "C" void kernel_launch(void* const* d_in, const int* in_sizes, int n_in,
                              void* d_out, int out_size, void* d_ws, size_t ws_size,
                              hipStream_t stream) {
    const float* x        = (const float*)d_in[0];
    const int*   eidx     = (const int*)d_in[1];
    const float* convW    = (const float*)d_in[2];
    const float* convB    = (const float*)d_in[3];
    const float* chanW1   = (const float*)d_in[4];
    const float* chanB1   = (const float*)d_in[5];
    const float* chanW2   = (const float*)d_in[6];
    const float* chanB2   = (const float*)d_in[7];
    const float* chanW3   = (const float*)d_in[8];
    const float* chanB3   = (const float*)d_in[9];
    float* out = (float*)d_out;

    const int N = in_sizes[0] / D;      // 100000
    const int E = in_sizes[1] / 2;      // 1600000
    const int* srcp = eidx;
    const int* dstp = eidx + E;

    char* w = (char*)d_ws;
    auto take = [&](size_t bytes) {
        char* p = w;
        w += (bytes + 255) & ~(size_t)255;
        return p;
    };
    float*  h0     = (float*)take((size_t)N * D * 4);
    float*  h1     = (float*)take((size_t)N * D * 4);
    float*  h2     = (float*)take((size_t)N * D * 4);
    int*    deg    = (int*)take((size_t)N * 4);
    int*    offs   = (int*)take((size_t)(N + 1) * 4);
    int*    cursor = (int*)take((size_t)N * 4);
    ushort* Wt1b   = (ushort*)take((size_t)NCH * 256 * 512 * 2);  // 1 MB
    ushort* Wt2b   = (ushort*)take((size_t)NCH * 256 * 256 * 2);  // 0.5 MB

    size_t used = (size_t)(w - (char*)d_ws);
    if (used > ws_size) return;
    size_t rem = ws_size - used;
    size_t need_csr = (size_t)E * 4;
    if (rem < need_csr || rem < (size_t)128 * 512) return;

    int*    csr = (int*)w;       // GIN phase only
    ushort* t1  = (ushort*)w;    // channel phase only (overlaps csr)
    long rcap = (long)(rem / 512);                  // bf16 t1: 512 B/row
    int R = (int)((rcap / 128) * 128);
    const int Nup = ((N + 127) / 128) * 128;
    if (R > Nup) R = Nup;

    // --- CSR build ---
    hipMemsetAsync(deg, 0, (size_t)N * 4, stream);
    hist_kernel<<<(E + 255) / 256, 256, 0, stream>>>(dstp, deg, E);
    scan_kernel<<<1, 1024, 0, stream>>>(deg, offs, cursor, N);
    fill_kernel<<<(E + 255) / 256, 256, 0, stream>>>(srcp, dstp, cursor, csr, E);

    // --- channel weight transpose+cvt (independent of GIN) ---
    cvtW_kernel<<<dim3(512 / 32, 256 / 32, NCH), 256, 0, stream>>>(chanW1, Wt1b, 512, 256);
    cvtW_kernel<<<dim3(256 / 32, 256 / 32, NCH), 256, 0, stream>>>(chanW2, Wt2b, 256, 256);

    const int rowtiles = (N + TM - 1) / TM;
    const int aggblocks = (N * 64 + 255) / 256;

    // --- GIN layers (fp32) ---
    float* hbuf[NLAYER] = {h0, h1, h2};
    const float* prev = x;
    for (int l = 0; l < NLAYER; ++l) {
        agg_kernel<<<aggblocks, 256, 0, stream>>>(prev, offs, csr, hbuf[l], N);
        for (int k = 0; k < 3; ++k) {
            const float* Wk = convW + ((size_t)(l * 3 + k)) * D * D;
            const float* Bk = convB + ((size_t)(l * 3 + k)) * D;
            gemm128_relu<<<rowtiles, 256, 0, stream>>>(hbuf[l], Wk, Bk, hbuf[l], N);
        }
        prev = hbuf[l];
    }

    // --- channel MLPs (bf16 MFMA), chunked over rows ---
    for (int r0 = 0; r0 < N; r0 += R) {
        int rows = N - r0; if (rows > R) rows = R;
        int rt128 = (rows + 127) / 128;
        int rt64  = (rows + 63) / 64;
        for (int c = 0; c < NCH; ++c) {
            chan_l1_mfma<<<dim3(rt128, 2), 256, 0, stream>>>(
                x, h0, h1, h2,
                Wt1b + (size_t)c * 256 * 512,
                chanB1 + (size_t)c * 256,
                t1, r0, rows, N);
            chan_l23_mfma<<<rt64, 256, 0, stream>>>(
                t1,
                Wt2b + (size_t)c * 256 * 256,
                chanB2 + (size_t)c * 256,
                chanW3 + (size_t)c * 256,
                chanB3 + c,
                out, r0, rows, c);
        }
    }
}

// Round 4
// 1245.099 us; speedup vs baseline: 3.3817x; 1.6358x over previous
//
#include <hip/hip_runtime.h>
#include <hip/hip_bf16.h>

// Problem constants (fixed by the reference)
#define D 128        // feature dim
#define NLAYER 3
#define NCH 4

typedef __attribute__((ext_vector_type(8))) short short8;
typedef __attribute__((ext_vector_type(4))) float f32x4;

__device__ __forceinline__ ushort f2bf(float f) {
    unsigned int u = __builtin_bit_cast(unsigned int, f);
    u += 0x7fffu + ((u >> 16) & 1u);     // RNE
    return (ushort)(u >> 16);
}
__device__ __forceinline__ float bflo(unsigned int u) {   // low bf16 -> f32
    return __builtin_bit_cast(float, u << 16);
}
__device__ __forceinline__ float bfhi(unsigned int u) {   // high bf16 -> f32
    return __builtin_bit_cast(float, u & 0xffff0000u);
}

// ---------------------------------------------------------------------------
// CSR construction
// ---------------------------------------------------------------------------
__global__ void hist_kernel(const int* __restrict__ dst, int* __restrict__ deg, int E) {
    int e = blockIdx.x * 256 + threadIdx.x;
    if (e < E) atomicAdd(&deg[dst[e]], 1);
}

// phase 1: per-block (256 elems) sums
__global__ __launch_bounds__(256) void blocksum_kernel(
    const int* __restrict__ deg, int* __restrict__ bsum, int n)
{
    int i = blockIdx.x * 256 + threadIdx.x;
    int v = (i < n) ? deg[i] : 0;
#pragma unroll
    for (int o = 1; o < 64; o <<= 1) v += __shfl_xor(v, o);
    __shared__ int s[4];
    if ((threadIdx.x & 63) == 0) s[threadIdx.x >> 6] = v;
    __syncthreads();
    if (threadIdx.x == 0) bsum[blockIdx.x] = s[0] + s[1] + s[2] + s[3];
}

// phase 2: single-block scan of block sums (nb <= 512)
__global__ __launch_bounds__(512) void scanblk_kernel(
    const int* __restrict__ bsum, int* __restrict__ boff, int nb,
    int* __restrict__ offs, int n, int E)
{
    __shared__ int sh[512];
    int t = threadIdx.x;
    sh[t] = (t < nb) ? bsum[t] : 0;
    __syncthreads();
    for (int d = 1; d < 512; d <<= 1) {
        int v = (t >= d) ? sh[t - d] : 0;
        __syncthreads();
        sh[t] += v;
        __syncthreads();
    }
    if (t < nb) boff[t] = (t == 0) ? 0 : sh[t - 1];
    if (t == 0) offs[n] = E;
}

// phase 3: per-block exclusive scan + block offset
__global__ __launch_bounds__(256) void blockscan_kernel(
    const int* __restrict__ deg, const int* __restrict__ boff,
    int* __restrict__ offs, int* __restrict__ cursor, int n)
{
    __shared__ int sh[256];
    int t = threadIdx.x;
    int i = blockIdx.x * 256 + t;
    int v = (i < n) ? deg[i] : 0;
    sh[t] = v;
    __syncthreads();
    for (int d = 1; d < 256; d <<= 1) {
        int u = (t >= d) ? sh[t - d] : 0;
        __syncthreads();
        sh[t] += u;
        __syncthreads();
    }
    if (i < n) {
        int ex = boff[blockIdx.x] + sh[t] - v;
        offs[i] = ex; cursor[i] = ex;
    }
}

__global__ void fill_kernel(const int* __restrict__ src, const int* __restrict__ dst,
                            int* __restrict__ cursor, int* __restrict__ csr, int E) {
    int e = blockIdx.x * 256 + threadIdx.x;
    if (e < E) {
        int p = atomicAdd(&cursor[dst[e]], 1);
        csr[p] = src[e];
    }
}

// ---------------------------------------------------------------------------
// fp32 -> bf16 bulk convert (8 elems/thread)
// ---------------------------------------------------------------------------
__global__ __launch_bounds__(256) void cvtx_kernel(
    const float* __restrict__ x, ushort* __restrict__ xb, int total8)
{
    int i = blockIdx.x * 256 + threadIdx.x;
    if (i >= total8) return;
    const float* gp = x + (size_t)i * 8;
    float4 v0 = *(const float4*)gp;
    float4 v1 = *(const float4*)(gp + 4);
    short8 pk;
    pk[0] = (short)f2bf(v0.x); pk[1] = (short)f2bf(v0.y);
    pk[2] = (short)f2bf(v0.z); pk[3] = (short)f2bf(v0.w);
    pk[4] = (short)f2bf(v1.x); pk[5] = (short)f2bf(v1.y);
    pk[6] = (short)f2bf(v1.z); pk[7] = (short)f2bf(v1.w);
    *(short8*)(xb + (size_t)i * 8) = pk;
}

// ---------------------------------------------------------------------------
// Weight transpose + fp32->bf16: Wt[c][n][k] = bf16(W[c][k][n])
// ---------------------------------------------------------------------------
__global__ void cvtW_kernel(const float* __restrict__ W, ushort* __restrict__ Wt,
                            int K, int Ncols) {
    __shared__ float tile[32][33];
    int c = blockIdx.z;
    int k0 = blockIdx.x * 32, n0 = blockIdx.y * 32;
    const float* Wc = W + (size_t)c * K * Ncols;
    ushort* Wtc = Wt + (size_t)c * K * Ncols;
    int tx = threadIdx.x & 31, ty = threadIdx.x >> 5;
#pragma unroll
    for (int i = 0; i < 4; ++i) {
        int k = k0 + ty + i * 8;
        tile[ty + i * 8][tx] = Wc[(size_t)k * Ncols + n0 + tx];
    }
    __syncthreads();
#pragma unroll
    for (int i = 0; i < 4; ++i) {
        int n = n0 + ty + i * 8;
        Wtc[(size_t)n * K + k0 + tx] = f2bf(tile[tx][ty + i * 8]);
    }
}

// ---------------------------------------------------------------------------
// Aggregation (bf16 in/out, fp32 accumulate):
//   out[n] = h[n] + sum_{j in N(n)} h[src_j];  rows are 128 bf16 = 64 uints.
// One wave per node; lane holds one uint (2 bf16).
// ---------------------------------------------------------------------------
__global__ __launch_bounds__(256) void agg_bf16(
    const ushort* __restrict__ h,
    const int* __restrict__ offs, const int* __restrict__ csr,
    ushort* __restrict__ outb, int n)
{
    int wid = (blockIdx.x * 256 + threadIdx.x) >> 6;
    int lane = threadIdx.x & 63;
    if (wid >= n) return;
    const unsigned int* hb = (const unsigned int*)h;
    unsigned int u = hb[(size_t)wid * 64 + lane];
    float ax = bflo(u), ay = bfhi(u);
    int b = offs[wid], e = offs[wid + 1];
    int j = b;
    for (; j + 2 <= e; j += 2) {
        int s0 = csr[j], s1 = csr[j + 1];
        unsigned int u0 = hb[(size_t)s0 * 64 + lane];
        unsigned int u1 = hb[(size_t)s1 * 64 + lane];
        ax += bflo(u0) + bflo(u1);
        ay += bfhi(u0) + bfhi(u1);
    }
    if (j < e) {
        unsigned int u0 = hb[(size_t)csr[j] * 64 + lane];
        ax += bflo(u0); ay += bfhi(u0);
    }
    unsigned int po = (unsigned int)f2bf(ax) | ((unsigned int)f2bf(ay) << 16);
    ((unsigned int*)outb)[(size_t)wid * 64 + lane] = po;
}

// ---------------------------------------------------------------------------
// Conv linear, bf16 MFMA: Out = relu(A @ W + b), A [N,128] bf16, Wt [128][128]
// bf16 k-contiguous, Out [N,128] bf16. Tile 128x128, 4 waves 64x64, BK=64.
// In-place safe (Out==A): all LDS stages precede the epilogue writes and each
// block touches only its own 128 rows.
// ---------------------------------------------------------------------------
__global__ __launch_bounds__(256) void conv_mfma(
    const ushort* __restrict__ A,
    const ushort* __restrict__ Wt,
    const float* __restrict__ bias,
    ushort* __restrict__ Out,
    int nrows)
{
    __shared__ __align__(16) ushort As[128 * 64];
    __shared__ __align__(16) ushort Bs[128 * 64];
    const int t = threadIdx.x;
    const int w = t >> 6, lane = t & 63;
    const int quad = lane >> 4, c15 = lane & 15;
    const int wr = w >> 1, wc = w & 1;
    const int rowbase = blockIdx.x * 128;

    f32x4 acc[4][4];
#pragma unroll
    for (int i = 0; i < 4; ++i)
#pragma unroll
        for (int j = 0; j < 4; ++j)
#pragma unroll
            for (int r = 0; r < 4; ++r) acc[i][j][r] = 0.f;

    for (int kc = 0; kc < 128; kc += 64) {
#pragma unroll
        for (int i = 0; i < 4; ++i) {
            int lin = (i * 4 + w) * 64 + lane;
            int row = lin >> 3, slot = lin & 7, g = slot ^ (row & 7);
            int grow = rowbase + row;
            if (grow >= nrows) grow = 0;
            const ushort* gp = A + (size_t)grow * 128 + kc + g * 8;
            __builtin_amdgcn_global_load_lds(
                (const __attribute__((address_space(1))) void*)gp,
                (__attribute__((address_space(3))) void*)&As[(i * 4 + w) * 512],
                16, 0, 0);
        }
#pragma unroll
        for (int i = 0; i < 4; ++i) {
            int lin = (i * 4 + w) * 64 + lane;
            int n = lin >> 3, slot = lin & 7, g = slot ^ (n & 7);
            const ushort* gp = Wt + (size_t)n * 128 + kc + g * 8;
            __builtin_amdgcn_global_load_lds(
                (const __attribute__((address_space(1))) void*)gp,
                (__attribute__((address_space(3))) void*)&Bs[(i * 4 + w) * 512],
                16, 0, 0);
        }
        __syncthreads();
#pragma unroll
        for (int ks = 0; ks < 2; ++ks) {
            const int K8 = ks * 4;
            short8 af[4], bf[4];
#pragma unroll
            for (int tr = 0; tr < 4; ++tr) {
                int r = wr * 64 + tr * 16 + c15;
                af[tr] = *(const short8*)&As[r * 64 + (((K8 + quad) ^ (r & 7)) * 8)];
            }
#pragma unroll
            for (int tc = 0; tc < 4; ++tc) {
                int n = wc * 64 + tc * 16 + c15;
                bf[tc] = *(const short8*)&Bs[n * 64 + (((K8 + quad) ^ (n & 7)) * 8)];
            }
#pragma unroll
            for (int tr = 0; tr < 4; ++tr)
#pragma unroll
                for (int tc = 0; tc < 4; ++tc)
                    acc[tr][tc] = __builtin_amdgcn_mfma_f32_16x16x32_bf16(
                        af[tr], bf[tc], acc[tr][tc], 0, 0, 0);
        }
        __syncthreads();
    }

#pragma unroll
    for (int tc = 0; tc < 4; ++tc) {
        int col = wc * 64 + tc * 16 + c15;
        float bv = bias[col];
#pragma unroll
        for (int tr = 0; tr < 4; ++tr)
#pragma unroll
            for (int rg = 0; rg < 4; ++rg) {
                int grow = rowbase + wr * 64 + tr * 16 + quad * 4 + rg;
                if (grow < nrows)
                    Out[(size_t)grow * 128 + col] = f2bf(fmaxf(acc[tr][tc][rg] + bv, 0.f));
            }
    }
}

// ---------------------------------------------------------------------------
// Channel layer 1, bf16 MFMA: T1 = relu(concat{xb,h0,h1,h2} @ W1 + b1), bf16.
// A slices bf16 [N,128]; B = Wt [256][512] bf16 k-contiguous.
// Tile 128x128 (grid y = 2 col tiles), 4 waves 64x64, BK=64.
// ---------------------------------------------------------------------------
__global__ __launch_bounds__(256) void chan_l1_mfma(
    const ushort* __restrict__ A0, const ushort* __restrict__ A1,
    const ushort* __restrict__ A2, const ushort* __restrict__ A3,
    const ushort* __restrict__ Wt,
    const float* __restrict__ b1,
    ushort* __restrict__ T1,           // [rows][256] bf16 (chunk-local)
    int r0, int rows, int N)
{
    __shared__ __align__(16) ushort As[128 * 64];
    __shared__ __align__(16) ushort Bs[128 * 64];
    const int t = threadIdx.x;
    const int w = t >> 6, lane = t & 63;
    const int quad = lane >> 4, c15 = lane & 15;
    const int wr = w >> 1, wc = w & 1;
    const int rowbase = blockIdx.x * 128;
    const int colbase = blockIdx.y * 128;
    const ushort* Asrc[4] = {A0, A1, A2, A3};

    f32x4 acc[4][4];
#pragma unroll
    for (int i = 0; i < 4; ++i)
#pragma unroll
        for (int j = 0; j < 4; ++j)
#pragma unroll
            for (int r = 0; r < 4; ++r) acc[i][j][r] = 0.f;

    for (int kc = 0; kc < 512; kc += 64) {
        const ushort* Ab = Asrc[kc >> 7];
        const int within = kc & 127;
#pragma unroll
        for (int i = 0; i < 4; ++i) {
            int lin = (i * 4 + w) * 64 + lane;
            int row = lin >> 3, slot = lin & 7, g = slot ^ (row & 7);
            int grow = r0 + rowbase + row;
            if (grow >= N) grow = r0;
            const ushort* gp = Ab + (size_t)grow * 128 + within + g * 8;
            __builtin_amdgcn_global_load_lds(
                (const __attribute__((address_space(1))) void*)gp,
                (__attribute__((address_space(3))) void*)&As[(i * 4 + w) * 512],
                16, 0, 0);
        }
#pragma unroll
        for (int i = 0; i < 4; ++i) {
            int lin = (i * 4 + w) * 64 + lane;
            int n = lin >> 3, slot = lin & 7, g = slot ^ (n & 7);
            const ushort* gp = Wt + (size_t)(colbase + n) * 512 + kc + g * 8;
            __builtin_amdgcn_global_load_lds(
                (const __attribute__((address_space(1))) void*)gp,
                (__attribute__((address_space(3))) void*)&Bs[(i * 4 + w) * 512],
                16, 0, 0);
        }
        __syncthreads();
#pragma unroll
        for (int ks = 0; ks < 2; ++ks) {
            const int K8 = ks * 4;
            short8 af[4], bf[4];
#pragma unroll
            for (int tr = 0; tr < 4; ++tr) {
                int r = wr * 64 + tr * 16 + c15;
                af[tr] = *(const short8*)&As[r * 64 + (((K8 + quad) ^ (r & 7)) * 8)];
            }
#pragma unroll
            for (int tc = 0; tc < 4; ++tc) {
                int n = wc * 64 + tc * 16 + c15;
                bf[tc] = *(const short8*)&Bs[n * 64 + (((K8 + quad) ^ (n & 7)) * 8)];
            }
#pragma unroll
            for (int tr = 0; tr < 4; ++tr)
#pragma unroll
                for (int tc = 0; tc < 4; ++tc)
                    acc[tr][tc] = __builtin_amdgcn_mfma_f32_16x16x32_bf16(
                        af[tr], bf[tc], acc[tr][tc], 0, 0, 0);
        }
        __syncthreads();
    }

#pragma unroll
    for (int tc = 0; tc < 4; ++tc) {
        int col = colbase + wc * 64 + tc * 16 + c15;
        float bias = b1[col];
#pragma unroll
        for (int tr = 0; tr < 4; ++tr)
#pragma unroll
            for (int rg = 0; rg < 4; ++rg) {
                int lrow = rowbase + wr * 64 + tr * 16 + quad * 4 + rg;
                if (lrow < rows)
                    T1[(size_t)lrow * 256 + col] = f2bf(fmaxf(acc[tr][tc][rg] + bias, 0.f));
            }
    }
}

// ---------------------------------------------------------------------------
// Channel layers 2+3 fused, bf16 MFMA (unchanged from R3).
// ---------------------------------------------------------------------------
__global__ __launch_bounds__(256) void chan_l23_mfma(
    const ushort* __restrict__ T1,
    const ushort* __restrict__ Wt2,
    const float* __restrict__ b2,
    const float* __restrict__ w3,
    const float* __restrict__ b3,
    float* __restrict__ out,
    int r0, int rows, int c)
{
    __shared__ __align__(16) ushort As[64 * 64];
    __shared__ __align__(16) ushort Bs[256 * 64];
    __shared__ float red[64][4];
    const int t = threadIdx.x;
    const int w = t >> 6, lane = t & 63;
    const int quad = lane >> 4, c15 = lane & 15;
    const int rowbase = blockIdx.x * 64;

    f32x4 acc[4][4];
#pragma unroll
    for (int i = 0; i < 4; ++i)
#pragma unroll
        for (int j = 0; j < 4; ++j)
#pragma unroll
            for (int r = 0; r < 4; ++r) acc[i][j][r] = 0.f;

    for (int kc = 0; kc < 256; kc += 64) {
#pragma unroll
        for (int i = 0; i < 2; ++i) {
            int lin = (i * 4 + w) * 64 + lane;
            int row = lin >> 3, slot = lin & 7, g = slot ^ (row & 7);
            int lrow = rowbase + row;
            if (lrow >= rows) lrow = 0;
            const ushort* gp = T1 + (size_t)lrow * 256 + kc + g * 8;
            __builtin_amdgcn_global_load_lds(
                (const __attribute__((address_space(1))) void*)gp,
                (__attribute__((address_space(3))) void*)&As[(i * 4 + w) * 512],
                16, 0, 0);
        }
#pragma unroll
        for (int i = 0; i < 8; ++i) {
            int lin = (i * 4 + w) * 64 + lane;
            int n = lin >> 3, slot = lin & 7, g = slot ^ (n & 7);
            const ushort* gp = Wt2 + (size_t)n * 256 + kc + g * 8;
            __builtin_amdgcn_global_load_lds(
                (const __attribute__((address_space(1))) void*)gp,
                (__attribute__((address_space(3))) void*)&Bs[(i * 4 + w) * 512],
                16, 0, 0);
        }
        __syncthreads();
#pragma unroll
        for (int ks = 0; ks < 2; ++ks) {
            const int K8 = ks * 4;
            short8 af[4], bf[4];
#pragma unroll
            for (int tr = 0; tr < 4; ++tr) {
                int r = tr * 16 + c15;
                af[tr] = *(const short8*)&As[r * 64 + (((K8 + quad) ^ (r & 7)) * 8)];
            }
#pragma unroll
            for (int tc = 0; tc < 4; ++tc) {
                int n = w * 64 + tc * 16 + c15;
                bf[tc] = *(const short8*)&Bs[n * 64 + (((K8 + quad) ^ (n & 7)) * 8)];
            }
#pragma unroll
            for (int tr = 0; tr < 4; ++tr)
#pragma unroll
                for (int tc = 0; tc < 4; ++tc)
                    acc[tr][tc] = __builtin_amdgcn_mfma_f32_16x16x32_bf16(
                        af[tr], bf[tc], acc[tr][tc], 0, 0, 0);
        }
        __syncthreads();
    }

    float b2v[4], w3v[4];
#pragma unroll
    for (int tc = 0; tc < 4; ++tc) {
        int col = w * 64 + tc * 16 + c15;
        b2v[tc] = b2[col];
        w3v[tc] = w3[col];
    }
#pragma unroll
    for (int tr = 0; tr < 4; ++tr)
#pragma unroll
        for (int rg = 0; rg < 4; ++rg) {
            float p = 0.f;
#pragma unroll
            for (int tc = 0; tc < 4; ++tc)
                p += fmaxf(acc[tr][tc][rg] + b2v[tc], 0.f) * w3v[tc];
            p += __shfl_xor(p, 1);
            p += __shfl_xor(p, 2);
            p += __shfl_xor(p, 4);
            p += __shfl_xor(p, 8);
            if (c15 == 0) red[tr * 16 + quad * 4 + rg][w] = p;
        }
    __syncthreads();
    if (t < 64) {
        int lrow = rowbase + t;
        if (lrow < rows) {
            float s = red[t][0] + red[t][1] + red[t][2] + red[t][3] + b3[0];
            out[(size_t)(r0 + lrow) * NCH + c] = fmaxf(s, 0.f);
        }
    }
}

// ---------------------------------------------------------------------------
// Launch
// ---------------------------------------------------------------------------
extern "C" void kernel_launch(void* const* d_in, const int* in_sizes, int n_in,
                              void* d_out, int out_size, void* d_ws, size_t ws_size,
                              hipStream_t stream) {
    const float* x        = (const float*)d_in[0];
    const int*   eidx     = (const int*)d_in[1];
    const float* convW    = (const float*)d_in[2];
    const float* convB    = (const float*)d_in[3];
    const float* chanW1   = (const float*)d_in[4];
    const float* chanB1   = (const float*)d_in[5];
    const float* chanW2   = (const float*)d_in[6];
    const float* chanB2   = (const float*)d_in[7];
    const float* chanW3   = (const float*)d_in[8];
    const float* chanB3   = (const float*)d_in[9];
    float* out = (float*)d_out;

    const int N = in_sizes[0] / D;      // 100000
    const int E = in_sizes[1] / 2;      // 1600000
    const int* srcp = eidx;
    const int* dstp = eidx + E;
    const int nb = (N + 255) / 256;     // 391

    char* w = (char*)d_ws;
    auto take = [&](size_t bytes) {
        char* p = w;
        w += (bytes + 255) & ~(size_t)255;
        return p;
    };
    ushort* xb     = (ushort*)take((size_t)N * D * 2);            // 25.6 MB
    ushort* h0     = (ushort*)take((size_t)N * D * 2);
    ushort* h1     = (ushort*)take((size_t)N * D * 2);
    ushort* h2     = (ushort*)take((size_t)N * D * 2);
    int*    deg    = (int*)take((size_t)N * 4);
    int*    offs   = (int*)take((size_t)(N + 1) * 4);
    int*    cursor = (int*)take((size_t)N * 4);
    int*    bsum   = (int*)take((size_t)nb * 4);
    int*    boff   = (int*)take((size_t)nb * 4);
    ushort* Wt1b   = (ushort*)take((size_t)NCH * 256 * 512 * 2);  // 1 MB
    ushort* Wt2b   = (ushort*)take((size_t)NCH * 256 * 256 * 2);  // 0.5 MB
    ushort* WtC    = (ushort*)take((size_t)NLAYER * 3 * D * D * 2); // 288 KB

    size_t used = (size_t)(w - (char*)d_ws);
    if (used > ws_size) return;
    size_t rem = ws_size - used;
    // GIN-phase overlay: csr (E ints) + a (N*128 bf16); channel phase: t1
    size_t need_gin = (((size_t)E * 4 + 255) & ~(size_t)255) + (size_t)N * D * 2;
    if (rem < need_gin || rem < (size_t)128 * 512) return;

    int*    csr = (int*)w;
    ushort* a   = (ushort*)(w + (((size_t)E * 4 + 255) & ~(size_t)255));
    ushort* t1  = (ushort*)w;                       // channel phase only
    long rcap = (long)(rem / 512);                  // bf16 t1: 512 B/row
    int R = (int)((rcap / 128) * 128);
    const int Nup = ((N + 127) / 128) * 128;
    if (R > Nup) R = Nup;

    // --- CSR build (parallel scan) ---
    hipMemsetAsync(deg, 0, (size_t)N * 4, stream);
    hist_kernel<<<(E + 255) / 256, 256, 0, stream>>>(dstp, deg, E);
    blocksum_kernel<<<nb, 256, 0, stream>>>(deg, bsum, N);
    scanblk_kernel<<<1, 512, 0, stream>>>(bsum, boff, nb, offs, N, E);
    blockscan_kernel<<<nb, 256, 0, stream>>>(deg, boff, offs, cursor, N);
    fill_kernel<<<(E + 255) / 256, 256, 0, stream>>>(srcp, dstp, cursor, csr, E);

    // --- converts (independent) ---
    cvtx_kernel<<<(N * 16 + 255) / 256, 256, 0, stream>>>(x, xb, N * 16);
    cvtW_kernel<<<dim3(512 / 32, 256 / 32, NCH), 256, 0, stream>>>(chanW1, Wt1b, 512, 256);
    cvtW_kernel<<<dim3(256 / 32, 256 / 32, NCH), 256, 0, stream>>>(chanW2, Wt2b, 256, 256);
    cvtW_kernel<<<dim3(D / 32, D / 32, NLAYER * 3), 256, 0, stream>>>(convW, WtC, D, D);

    const int rowtiles = (N + 127) / 128;
    const int aggblocks = (N * 64 + 255) / 256;

    // --- GIN layers (bf16 MFMA) ---
    ushort* hbuf[NLAYER] = {h0, h1, h2};
    const ushort* prev = xb;
    for (int l = 0; l < NLAYER; ++l) {
        agg_bf16<<<aggblocks, 256, 0, stream>>>(prev, offs, csr, a, N);
        for (int k = 0; k < 3; ++k) {
            const ushort* Wk = WtC + (size_t)(l * 3 + k) * D * D;
            const float* Bk = convB + (size_t)(l * 3 + k) * D;
            ushort* dst_ = (k == 2) ? hbuf[l] : a;
            conv_mfma<<<rowtiles, 256, 0, stream>>>(a, Wk, Bk, dst_, N);
        }
        prev = hbuf[l];
    }

    // --- channel MLPs (bf16 MFMA), chunked over rows ---
    for (int r0 = 0; r0 < N; r0 += R) {
        int rows = N - r0; if (rows > R) rows = R;
        int rt128 = (rows + 127) / 128;
        int rt64  = (rows + 63) / 64;
        for (int c = 0; c < NCH; ++c) {
            chan_l1_mfma<<<dim3(rt128, 2), 256, 0, stream>>>(
                xb, h0, h1, h2,
                Wt1b + (size_t)c * 256 * 512,
                chanB1 + (size_t)c * 256,
                t1, r0, rows, N);
            chan_l23_mfma<<<rt64, 256, 0, stream>>>(
                t1,
                Wt2b + (size_t)c * 256 * 256,
                chanB2 + (size_t)c * 256,
                chanW3 + (size_t)c * 256,
                chanB3 + c,
                out, r0, rows, c);
        }
    }
}

// Round 5
// 983.085 us; speedup vs baseline: 4.2830x; 1.2665x over previous
//
#include <hip/hip_runtime.h>
#include <hip/hip_bf16.h>

// Problem constants (fixed by the reference)
#define D 128        // feature dim
#define NLAYER 3
#define NCH 4

typedef __attribute__((ext_vector_type(8))) short short8;
typedef __attribute__((ext_vector_type(4))) float f32x4;

__device__ __forceinline__ ushort f2bf(float f) {
    unsigned int u = __builtin_bit_cast(unsigned int, f);
    u += 0x7fffu + ((u >> 16) & 1u);     // RNE
    return (ushort)(u >> 16);
}
__device__ __forceinline__ float bflo(unsigned int u) {
    return __builtin_bit_cast(float, u << 16);
}
__device__ __forceinline__ float bfhi(unsigned int u) {
    return __builtin_bit_cast(float, u & 0xffff0000u);
}

// ---------------------------------------------------------------------------
// CSR construction
// ---------------------------------------------------------------------------
__global__ void hist_kernel(const int* __restrict__ dst, int* __restrict__ deg, int E) {
    int e = blockIdx.x * 256 + threadIdx.x;
    if (e < E) atomicAdd(&deg[dst[e]], 1);
}

__global__ __launch_bounds__(256) void blocksum_kernel(
    const int* __restrict__ deg, int* __restrict__ bsum, int n)
{
    int i = blockIdx.x * 256 + threadIdx.x;
    int v = (i < n) ? deg[i] : 0;
#pragma unroll
    for (int o = 1; o < 64; o <<= 1) v += __shfl_xor(v, o);
    __shared__ int s[4];
    if ((threadIdx.x & 63) == 0) s[threadIdx.x >> 6] = v;
    __syncthreads();
    if (threadIdx.x == 0) bsum[blockIdx.x] = s[0] + s[1] + s[2] + s[3];
}

__global__ __launch_bounds__(512) void scanblk_kernel(
    const int* __restrict__ bsum, int* __restrict__ boff, int nb,
    int* __restrict__ offs, int n, int E)
{
    __shared__ int sh[512];
    int t = threadIdx.x;
    sh[t] = (t < nb) ? bsum[t] : 0;
    __syncthreads();
    for (int d = 1; d < 512; d <<= 1) {
        int v = (t >= d) ? sh[t - d] : 0;
        __syncthreads();
        sh[t] += v;
        __syncthreads();
    }
    if (t < nb) boff[t] = (t == 0) ? 0 : sh[t - 1];
    if (t == 0) offs[n] = E;
}

__global__ __launch_bounds__(256) void blockscan_kernel(
    const int* __restrict__ deg, const int* __restrict__ boff,
    int* __restrict__ offs, int* __restrict__ cursor, int n)
{
    __shared__ int sh[256];
    int t = threadIdx.x;
    int i = blockIdx.x * 256 + t;
    int v = (i < n) ? deg[i] : 0;
    sh[t] = v;
    __syncthreads();
    for (int d = 1; d < 256; d <<= 1) {
        int u = (t >= d) ? sh[t - d] : 0;
        __syncthreads();
        sh[t] += u;
        __syncthreads();
    }
    if (i < n) {
        int ex = boff[blockIdx.x] + sh[t] - v;
        offs[i] = ex; cursor[i] = ex;
    }
}

// XCD-partitioned fill: class = blockIdx & 7 owns dst range
// [cls*nPer, (cls+1)*nPer). Each class scans all edges (L3-resident) but its
// csr writes land in one contiguous slice -> one XCD's L2, no line ping-pong.
#define FILL_CHUNK 4096
__global__ __launch_bounds__(256) void fill_part_kernel(
    const int* __restrict__ src, const int* __restrict__ dst,
    int* __restrict__ cursor, int* __restrict__ csr,
    int E, int nPer, int N)
{
    int cls = blockIdx.x & 7;
    int base = (blockIdx.x >> 3) * FILL_CHUNK;
    int lo = cls * nPer;
    int hi = lo + nPer; if (hi > N) hi = N;
    int end = base + FILL_CHUNK; if (end > E) end = E;
    for (int e = base + threadIdx.x; e < end; e += 256) {
        int d = dst[e];
        int s = src[e];
        if (d >= lo && d < hi) {
            int p = atomicAdd(&cursor[d], 1);
            csr[p] = s;
        }
    }
}

// ---------------------------------------------------------------------------
// fp32 -> bf16 bulk convert (8 elems/thread)
// ---------------------------------------------------------------------------
__global__ __launch_bounds__(256) void cvtx_kernel(
    const float* __restrict__ x, ushort* __restrict__ xb, int total8)
{
    int i = blockIdx.x * 256 + threadIdx.x;
    if (i >= total8) return;
    const float* gp = x + (size_t)i * 8;
    float4 v0 = *(const float4*)gp;
    float4 v1 = *(const float4*)(gp + 4);
    short8 pk;
    pk[0] = (short)f2bf(v0.x); pk[1] = (short)f2bf(v0.y);
    pk[2] = (short)f2bf(v0.z); pk[3] = (short)f2bf(v0.w);
    pk[4] = (short)f2bf(v1.x); pk[5] = (short)f2bf(v1.y);
    pk[6] = (short)f2bf(v1.z); pk[7] = (short)f2bf(v1.w);
    *(short8*)(xb + (size_t)i * 8) = pk;
}

// ---------------------------------------------------------------------------
// Weight transpose + fp32->bf16: Wt[c][n][k] = bf16(W[c][k][n])
// ---------------------------------------------------------------------------
__global__ void cvtW_kernel(const float* __restrict__ W, ushort* __restrict__ Wt,
                            int K, int Ncols) {
    __shared__ float tile[32][33];
    int c = blockIdx.z;
    int k0 = blockIdx.x * 32, n0 = blockIdx.y * 32;
    const float* Wc = W + (size_t)c * K * Ncols;
    ushort* Wtc = Wt + (size_t)c * K * Ncols;
    int tx = threadIdx.x & 31, ty = threadIdx.x >> 5;
#pragma unroll
    for (int i = 0; i < 4; ++i) {
        int k = k0 + ty + i * 8;
        tile[ty + i * 8][tx] = Wc[(size_t)k * Ncols + n0 + tx];
    }
    __syncthreads();
#pragma unroll
    for (int i = 0; i < 4; ++i) {
        int n = n0 + ty + i * 8;
        Wtc[(size_t)n * K + k0 + tx] = f2bf(tile[tx][ty + i * 8]);
    }
}

// ---------------------------------------------------------------------------
// Aggregation (bf16 in/out, fp32 accumulate), unroll x4.
// ---------------------------------------------------------------------------
__global__ __launch_bounds__(256) void agg_bf16(
    const ushort* __restrict__ h,
    const int* __restrict__ offs, const int* __restrict__ csr,
    ushort* __restrict__ outb, int n)
{
    int wid = (blockIdx.x * 256 + threadIdx.x) >> 6;
    int lane = threadIdx.x & 63;
    if (wid >= n) return;
    const unsigned int* hb = (const unsigned int*)h;
    unsigned int u = hb[(size_t)wid * 64 + lane];
    float ax = bflo(u), ay = bfhi(u);
    int b = offs[wid], e = offs[wid + 1];
    int j = b;
    for (; j + 4 <= e; j += 4) {
        int s0 = csr[j], s1 = csr[j + 1], s2 = csr[j + 2], s3 = csr[j + 3];
        unsigned int u0 = hb[(size_t)s0 * 64 + lane];
        unsigned int u1 = hb[(size_t)s1 * 64 + lane];
        unsigned int u2 = hb[(size_t)s2 * 64 + lane];
        unsigned int u3 = hb[(size_t)s3 * 64 + lane];
        ax += (bflo(u0) + bflo(u1)) + (bflo(u2) + bflo(u3));
        ay += (bfhi(u0) + bfhi(u1)) + (bfhi(u2) + bfhi(u3));
    }
    for (; j < e; ++j) {
        unsigned int u0 = hb[(size_t)csr[j] * 64 + lane];
        ax += bflo(u0); ay += bfhi(u0);
    }
    unsigned int po = (unsigned int)f2bf(ax) | ((unsigned int)f2bf(ay) << 16);
    ((unsigned int*)outb)[(size_t)wid * 64 + lane] = po;
}

// ---------------------------------------------------------------------------
// Fused GIN-layer MLP: Out = relu(relu(relu(A@W0+b0)@W1+b1)@W2+b2), all
// 128x128 bf16. Block = 128 rows, full K=128 in LDS; intermediates round-trip
// through LDS (bf16, same rounding points as the unfused version).
// ---------------------------------------------------------------------------
__global__ __launch_bounds__(256) void gin_mlp_mfma(
    const ushort* __restrict__ A,      // [N,128] bf16 (agg output)
    const ushort* __restrict__ WtL,    // [3][128][128] bf16, n-major
    const float* __restrict__ biasL,   // [3][128]
    ushort* __restrict__ Out,          // [N,128] bf16
    int nrows)
{
    __shared__ __align__(16) ushort As[128 * 128];   // 32 KB
    __shared__ __align__(16) ushort Bs[128 * 128];   // 32 KB
    const int t = threadIdx.x;
    const int w = t >> 6, lane = t & 63;
    const int quad = lane >> 4, c15 = lane & 15;
    const int wr = w >> 1, wc = w & 1;
    const int rowbase = blockIdx.x * 128;

    // stage A: 2048 granules, swizzle slot = g ^ (row & 15)
#pragma unroll
    for (int i = 0; i < 8; ++i) {
        int lin = (i * 4 + w) * 64 + lane;
        int row = lin >> 4, slot = lin & 15, g = slot ^ (row & 15);
        int grow = rowbase + row;
        if (grow >= nrows) grow = 0;
        const ushort* gp = A + (size_t)grow * 128 + g * 8;
        __builtin_amdgcn_global_load_lds(
            (const __attribute__((address_space(1))) void*)gp,
            (__attribute__((address_space(3))) void*)&As[(i * 4 + w) * 512],
            16, 0, 0);
    }
    // stage B0
#pragma unroll
    for (int i = 0; i < 8; ++i) {
        int lin = (i * 4 + w) * 64 + lane;
        int n = lin >> 4, slot = lin & 15, g = slot ^ (n & 15);
        const ushort* gp = WtL + (size_t)n * 128 + g * 8;
        __builtin_amdgcn_global_load_lds(
            (const __attribute__((address_space(1))) void*)gp,
            (__attribute__((address_space(3))) void*)&Bs[(i * 4 + w) * 512],
            16, 0, 0);
    }
    __syncthreads();

    for (int s = 0; s < 3; ++s) {
        f32x4 acc[4][4];
#pragma unroll
        for (int i = 0; i < 4; ++i)
#pragma unroll
            for (int j = 0; j < 4; ++j)
#pragma unroll
                for (int r = 0; r < 4; ++r) acc[i][j][r] = 0.f;

#pragma unroll
        for (int ks = 0; ks < 4; ++ks) {
            short8 af[4], bf[4];
#pragma unroll
            for (int tr = 0; tr < 4; ++tr) {
                int r = wr * 64 + tr * 16 + c15;
                af[tr] = *(const short8*)&As[r * 128 + (((ks * 4 + quad) ^ (r & 15)) * 8)];
            }
#pragma unroll
            for (int tc = 0; tc < 4; ++tc) {
                int n = wc * 64 + tc * 16 + c15;
                bf[tc] = *(const short8*)&Bs[n * 128 + (((ks * 4 + quad) ^ (n & 15)) * 8)];
            }
#pragma unroll
            for (int tr = 0; tr < 4; ++tr)
#pragma unroll
                for (int tc = 0; tc < 4; ++tc)
                    acc[tr][tc] = __builtin_amdgcn_mfma_f32_16x16x32_bf16(
                        af[tr], bf[tc], acc[tr][tc], 0, 0, 0);
        }
        __syncthreads();   // all As/Bs reads done

        if (s < 2) {
            // relu(acc+bias) -> As (bf16, swizzled); stage next B
#pragma unroll
            for (int tc = 0; tc < 4; ++tc) {
                int col = wc * 64 + tc * 16 + c15;
                float bv = biasL[s * 128 + col];
#pragma unroll
                for (int tr = 0; tr < 4; ++tr)
#pragma unroll
                    for (int rg = 0; rg < 4; ++rg) {
                        int row = wr * 64 + tr * 16 + quad * 4 + rg;
                        As[row * 128 + (((col >> 3) ^ (row & 15)) * 8) + (col & 7)]
                            = f2bf(fmaxf(acc[tr][tc][rg] + bv, 0.f));
                    }
            }
            const ushort* Wn = WtL + (size_t)(s + 1) * 128 * 128;
#pragma unroll
            for (int i = 0; i < 8; ++i) {
                int lin = (i * 4 + w) * 64 + lane;
                int n = lin >> 4, slot = lin & 15, g = slot ^ (n & 15);
                const ushort* gp = Wn + (size_t)n * 128 + g * 8;
                __builtin_amdgcn_global_load_lds(
                    (const __attribute__((address_space(1))) void*)gp,
                    (__attribute__((address_space(3))) void*)&Bs[(i * 4 + w) * 512],
                    16, 0, 0);
            }
            __syncthreads();
        } else {
            // final epilogue to global
#pragma unroll
            for (int tc = 0; tc < 4; ++tc) {
                int col = wc * 64 + tc * 16 + c15;
                float bv = biasL[2 * 128 + col];
#pragma unroll
                for (int tr = 0; tr < 4; ++tr)
#pragma unroll
                    for (int rg = 0; rg < 4; ++rg) {
                        int grow = rowbase + wr * 64 + tr * 16 + quad * 4 + rg;
                        if (grow < nrows)
                            Out[(size_t)grow * 128 + col]
                                = f2bf(fmaxf(acc[tr][tc][rg] + bv, 0.f));
                    }
            }
        }
    }
}

// ---------------------------------------------------------------------------
// Merged channel layer 1: T1 = relu(concat{xb,h0,h1,h2} @ W1all + b1all),
// W1all = [512,1024] (all 4 channels side by side; Wt layout [1024][512]
// n-major). Tile 128 rows x 256 cols (grid.y = 4), BK = 64. T1 bf16 stride 1024.
// ---------------------------------------------------------------------------
__global__ __launch_bounds__(256, 2) void chan_l1_mfma(
    const ushort* __restrict__ A0, const ushort* __restrict__ A1,
    const ushort* __restrict__ A2, const ushort* __restrict__ A3,
    const ushort* __restrict__ WtAll,  // [1024][512] bf16
    const float* __restrict__ b1all,   // [1024]
    ushort* __restrict__ T1,           // [rows][1024] bf16 (chunk-local)
    int r0, int rows, int N)
{
    __shared__ __align__(16) ushort As[128 * 64];   // 16 KB
    __shared__ __align__(16) ushort Bs[256 * 64];   // 32 KB
    const int t = threadIdx.x;
    const int w = t >> 6, lane = t & 63;
    const int quad = lane >> 4, c15 = lane & 15;
    const int wr = w >> 1, wc = w & 1;
    const int rowbase = blockIdx.x * 128;
    const int colbase = blockIdx.y * 256;
    const ushort* Asrc[4] = {A0, A1, A2, A3};

    f32x4 acc[4][8];
#pragma unroll
    for (int i = 0; i < 4; ++i)
#pragma unroll
        for (int j = 0; j < 8; ++j)
#pragma unroll
            for (int r = 0; r < 4; ++r) acc[i][j][r] = 0.f;

    for (int kc = 0; kc < 512; kc += 64) {
        const ushort* Ab = Asrc[kc >> 7];
        const int within = kc & 127;
#pragma unroll
        for (int i = 0; i < 4; ++i) {
            int lin = (i * 4 + w) * 64 + lane;
            int row = lin >> 3, slot = lin & 7, g = slot ^ (row & 7);
            int grow = r0 + rowbase + row;
            if (grow >= N) grow = r0;
            const ushort* gp = Ab + (size_t)grow * 128 + within + g * 8;
            __builtin_amdgcn_global_load_lds(
                (const __attribute__((address_space(1))) void*)gp,
                (__attribute__((address_space(3))) void*)&As[(i * 4 + w) * 512],
                16, 0, 0);
        }
#pragma unroll
        for (int i = 0; i < 8; ++i) {
            int lin = (i * 4 + w) * 64 + lane;
            int n = lin >> 3, slot = lin & 7, g = slot ^ (n & 7);
            const ushort* gp = WtAll + (size_t)(colbase + n) * 512 + kc + g * 8;
            __builtin_amdgcn_global_load_lds(
                (const __attribute__((address_space(1))) void*)gp,
                (__attribute__((address_space(3))) void*)&Bs[(i * 4 + w) * 512],
                16, 0, 0);
        }
        __syncthreads();
#pragma unroll
        for (int ks = 0; ks < 2; ++ks) {
            const int K8 = ks * 4;
            short8 af[4], bf[8];
#pragma unroll
            for (int tr = 0; tr < 4; ++tr) {
                int r = wr * 64 + tr * 16 + c15;
                af[tr] = *(const short8*)&As[r * 64 + (((K8 + quad) ^ (r & 7)) * 8)];
            }
#pragma unroll
            for (int tc = 0; tc < 8; ++tc) {
                int n = wc * 128 + tc * 16 + c15;
                bf[tc] = *(const short8*)&Bs[n * 64 + (((K8 + quad) ^ (n & 7)) * 8)];
            }
#pragma unroll
            for (int tr = 0; tr < 4; ++tr)
#pragma unroll
                for (int tc = 0; tc < 8; ++tc)
                    acc[tr][tc] = __builtin_amdgcn_mfma_f32_16x16x32_bf16(
                        af[tr], bf[tc], acc[tr][tc], 0, 0, 0);
        }
        __syncthreads();
    }

#pragma unroll
    for (int tc = 0; tc < 8; ++tc) {
        int col = colbase + wc * 128 + tc * 16 + c15;
        float bias = b1all[col];
#pragma unroll
        for (int tr = 0; tr < 4; ++tr)
#pragma unroll
            for (int rg = 0; rg < 4; ++rg) {
                int lrow = rowbase + wr * 64 + tr * 16 + quad * 4 + rg;
                if (lrow < rows)
                    T1[(size_t)lrow * 1024 + col] = f2bf(fmaxf(acc[tr][tc][rg] + bias, 0.f));
            }
    }
}

// ---------------------------------------------------------------------------
// Channel layers 2+3 fused (T1 row stride 1024, channel slice passed in base).
// ---------------------------------------------------------------------------
__global__ __launch_bounds__(256) void chan_l23_mfma(
    const ushort* __restrict__ T1c,    // T1 + c*256, stride 1024
    const ushort* __restrict__ Wt2,
    const float* __restrict__ b2,
    const float* __restrict__ w3,
    const float* __restrict__ b3,
    float* __restrict__ out,
    int r0, int rows, int c)
{
    __shared__ __align__(16) ushort As[64 * 64];
    __shared__ __align__(16) ushort Bs[256 * 64];
    __shared__ float red[64][4];
    const int t = threadIdx.x;
    const int w = t >> 6, lane = t & 63;
    const int quad = lane >> 4, c15 = lane & 15;
    const int rowbase = blockIdx.x * 64;

    f32x4 acc[4][4];
#pragma unroll
    for (int i = 0; i < 4; ++i)
#pragma unroll
        for (int j = 0; j < 4; ++j)
#pragma unroll
            for (int r = 0; r < 4; ++r) acc[i][j][r] = 0.f;

    for (int kc = 0; kc < 256; kc += 64) {
#pragma unroll
        for (int i = 0; i < 2; ++i) {
            int lin = (i * 4 + w) * 64 + lane;
            int row = lin >> 3, slot = lin & 7, g = slot ^ (row & 7);
            int lrow = rowbase + row;
            if (lrow >= rows) lrow = 0;
            const ushort* gp = T1c + (size_t)lrow * 1024 + kc + g * 8;
            __builtin_amdgcn_global_load_lds(
                (const __attribute__((address_space(1))) void*)gp,
                (__attribute__((address_space(3))) void*)&As[(i * 4 + w) * 512],
                16, 0, 0);
        }
#pragma unroll
        for (int i = 0; i < 8; ++i) {
            int lin = (i * 4 + w) * 64 + lane;
            int n = lin >> 3, slot = lin & 7, g = slot ^ (n & 7);
            const ushort* gp = Wt2 + (size_t)n * 256 + kc + g * 8;
            __builtin_amdgcn_global_load_lds(
                (const __attribute__((address_space(1))) void*)gp,
                (__attribute__((address_space(3))) void*)&Bs[(i * 4 + w) * 512],
                16, 0, 0);
        }
        __syncthreads();
#pragma unroll
        for (int ks = 0; ks < 2; ++ks) {
            const int K8 = ks * 4;
            short8 af[4], bf[4];
#pragma unroll
            for (int tr = 0; tr < 4; ++tr) {
                int r = tr * 16 + c15;
                af[tr] = *(const short8*)&As[r * 64 + (((K8 + quad) ^ (r & 7)) * 8)];
            }
#pragma unroll
            for (int tc = 0; tc < 4; ++tc) {
                int n = w * 64 + tc * 16 + c15;
                bf[tc] = *(const short8*)&Bs[n * 64 + (((K8 + quad) ^ (n & 7)) * 8)];
            }
#pragma unroll
            for (int tr = 0; tr < 4; ++tr)
#pragma unroll
                for (int tc = 0; tc < 4; ++tc)
                    acc[tr][tc] = __builtin_amdgcn_mfma_f32_16x16x32_bf16(
                        af[tr], bf[tc], acc[tr][tc], 0, 0, 0);
        }
        __syncthreads();
    }

    float b2v[4], w3v[4];
#pragma unroll
    for (int tc = 0; tc < 4; ++tc) {
        int col = w * 64 + tc * 16 + c15;
        b2v[tc] = b2[col];
        w3v[tc] = w3[col];
    }
#pragma unroll
    for (int tr = 0; tr < 4; ++tr)
#pragma unroll
        for (int rg = 0; rg < 4; ++rg) {
            float p = 0.f;
#pragma unroll
            for (int tc = 0; tc < 4; ++tc)
                p += fmaxf(acc[tr][tc][rg] + b2v[tc], 0.f) * w3v[tc];
            p += __shfl_xor(p, 1);
            p += __shfl_xor(p, 2);
            p += __shfl_xor(p, 4);
            p += __shfl_xor(p, 8);
            if (c15 == 0) red[tr * 16 + quad * 4 + rg][w] = p;
        }
    __syncthreads();
    if (t < 64) {
        int lrow = rowbase + t;
        if (lrow < rows) {
            float s = red[t][0] + red[t][1] + red[t][2] + red[t][3] + b3[0];
            out[(size_t)(r0 + lrow) * NCH + c] = fmaxf(s, 0.f);
        }
    }
}

// ---------------------------------------------------------------------------
// Launch
// ---------------------------------------------------------------------------
extern "C" void kernel_launch(void* const* d_in, const int* in_sizes, int n_in,
                              void* d_out, int out_size, void* d_ws, size_t ws_size,
                              hipStream_t stream) {
    const float* x        = (const float*)d_in[0];
    const int*   eidx     = (const int*)d_in[1];
    const float* convW    = (const float*)d_in[2];
    const float* convB    = (const float*)d_in[3];
    const float* chanW1   = (const float*)d_in[4];
    const float* chanB1   = (const float*)d_in[5];
    const float* chanW2   = (const float*)d_in[6];
    const float* chanB2   = (const float*)d_in[7];
    const float* chanW3   = (const float*)d_in[8];
    const float* chanB3   = (const float*)d_in[9];
    float* out = (float*)d_out;

    const int N = in_sizes[0] / D;      // 100000
    const int E = in_sizes[1] / 2;      // 1600000
    const int* srcp = eidx;
    const int* dstp = eidx + E;
    const int nb = (N + 255) / 256;     // 391

    char* w = (char*)d_ws;
    auto take = [&](size_t bytes) {
        char* p = w;
        w += (bytes + 255) & ~(size_t)255;
        return p;
    };
    ushort* xb     = (ushort*)take((size_t)N * D * 2);
    ushort* h0     = (ushort*)take((size_t)N * D * 2);
    ushort* h1     = (ushort*)take((size_t)N * D * 2);
    ushort* h2     = (ushort*)take((size_t)N * D * 2);
    int*    deg    = (int*)take((size_t)N * 4);
    int*    offs   = (int*)take((size_t)(N + 1) * 4);
    int*    cursor = (int*)take((size_t)N * 4);
    int*    bsum   = (int*)take((size_t)nb * 4);
    int*    boff   = (int*)take((size_t)nb * 4);
    ushort* Wt1b   = (ushort*)take((size_t)NCH * 256 * 512 * 2);
    ushort* Wt2b   = (ushort*)take((size_t)NCH * 256 * 256 * 2);
    ushort* WtC    = (ushort*)take((size_t)NLAYER * 3 * D * D * 2);

    size_t used = (size_t)(w - (char*)d_ws);
    if (used > ws_size) return;
    size_t rem = ws_size - used;
    size_t need_gin = (((size_t)E * 4 + 255) & ~(size_t)255) + (size_t)N * D * 2;
    if (rem < need_gin || rem < (size_t)128 * 2048) return;

    int*    csr = (int*)w;
    ushort* a   = (ushort*)(w + (((size_t)E * 4 + 255) & ~(size_t)255));
    ushort* t1  = (ushort*)w;                       // channel phase overlay
    long rcap = (long)(rem / 2048);                 // T1 row = 1024 bf16 = 2 KB
    int R = (int)((rcap / 128) * 128);
    const int Nup = ((N + 127) / 128) * 128;
    if (R > Nup) R = Nup;

    // --- CSR build (parallel scan + XCD-partitioned fill) ---
    hipMemsetAsync(deg, 0, (size_t)N * 4, stream);
    hist_kernel<<<(E + 255) / 256, 256, 0, stream>>>(dstp, deg, E);
    blocksum_kernel<<<nb, 256, 0, stream>>>(deg, bsum, N);
    scanblk_kernel<<<1, 512, 0, stream>>>(bsum, boff, nb, offs, N, E);
    blockscan_kernel<<<nb, 256, 0, stream>>>(deg, boff, offs, cursor, N);
    {
        int nchunks = (E + FILL_CHUNK - 1) / FILL_CHUNK;
        int nPer = (N + 7) / 8;
        fill_part_kernel<<<nchunks * 8, 256, 0, stream>>>(
            srcp, dstp, cursor, csr, E, nPer, N);
    }

    // --- converts (independent) ---
    cvtx_kernel<<<(N * 16 + 255) / 256, 256, 0, stream>>>(x, xb, N * 16);
    cvtW_kernel<<<dim3(512 / 32, 256 / 32, NCH), 256, 0, stream>>>(chanW1, Wt1b, 512, 256);
    cvtW_kernel<<<dim3(256 / 32, 256 / 32, NCH), 256, 0, stream>>>(chanW2, Wt2b, 256, 256);
    cvtW_kernel<<<dim3(D / 32, D / 32, NLAYER * 3), 256, 0, stream>>>(convW, WtC, D, D);

    const int rowtiles = (N + 127) / 128;
    const int aggblocks = (N * 64 + 255) / 256;

    // --- GIN layers: agg + fused 3-linear MLP per layer ---
    ushort* hbuf[NLAYER] = {h0, h1, h2};
    const ushort* prev = xb;
    for (int l = 0; l < NLAYER; ++l) {
        agg_bf16<<<aggblocks, 256, 0, stream>>>(prev, offs, csr, a, N);
        gin_mlp_mfma<<<rowtiles, 256, 0, stream>>>(
            a, WtC + (size_t)l * 3 * D * D, convB + (size_t)l * 3 * D, hbuf[l], N);
        prev = hbuf[l];
    }

    // --- channel MLPs: merged L1 GEMM + per-channel fused L2/L3 ---
    for (int r0 = 0; r0 < N; r0 += R) {
        int rows = N - r0; if (rows > R) rows = R;
        int rt128 = (rows + 127) / 128;
        int rt64  = (rows + 63) / 64;
        chan_l1_mfma<<<dim3(rt128, 4), 256, 0, stream>>>(
            xb, h0, h1, h2, Wt1b, chanB1, t1, r0, rows, N);
        for (int c = 0; c < NCH; ++c) {
            chan_l23_mfma<<<rt64, 256, 0, stream>>>(
                t1 + (size_t)c * 256,
                Wt2b + (size_t)c * 256 * 256,
                chanB2 + (size_t)c * 256,
                chanW3 + (size_t)c * 256,
                chanB3 + c,
                out, r0, rows, c);
        }
    }
}

// Round 6
// 868.473 us; speedup vs baseline: 4.8482x; 1.1320x over previous
//
#include <hip/hip_runtime.h>
#include <hip/hip_bf16.h>

// Problem constants (fixed by the reference)
#define D 128        // feature dim
#define NLAYER 3
#define NCH 4

typedef __attribute__((ext_vector_type(8))) short short8;
typedef __attribute__((ext_vector_type(4))) float f32x4;

__device__ __forceinline__ ushort f2bf(float f) {
    unsigned int u = __builtin_bit_cast(unsigned int, f);
    u += 0x7fffu + ((u >> 16) & 1u);     // RNE
    return (ushort)(u >> 16);
}
__device__ __forceinline__ float bflo(unsigned int u) {
    return __builtin_bit_cast(float, u << 16);
}
__device__ __forceinline__ float bfhi(unsigned int u) {
    return __builtin_bit_cast(float, u & 0xffff0000u);
}

// ---------------------------------------------------------------------------
// CSR construction
// ---------------------------------------------------------------------------
__global__ void hist_kernel(const int* __restrict__ dst, int* __restrict__ deg, int E) {
    int e = blockIdx.x * 256 + threadIdx.x;
    if (e < E) atomicAdd(&deg[dst[e]], 1);
}

__global__ __launch_bounds__(256) void blocksum_kernel(
    const int* __restrict__ deg, int* __restrict__ bsum, int n)
{
    int i = blockIdx.x * 256 + threadIdx.x;
    int v = (i < n) ? deg[i] : 0;
#pragma unroll
    for (int o = 1; o < 64; o <<= 1) v += __shfl_xor(v, o);
    __shared__ int s[4];
    if ((threadIdx.x & 63) == 0) s[threadIdx.x >> 6] = v;
    __syncthreads();
    if (threadIdx.x == 0) bsum[blockIdx.x] = s[0] + s[1] + s[2] + s[3];
}

__global__ __launch_bounds__(512) void scanblk_kernel(
    const int* __restrict__ bsum, int* __restrict__ boff, int nb,
    int* __restrict__ offs, int n, int E)
{
    __shared__ int sh[512];
    int t = threadIdx.x;
    sh[t] = (t < nb) ? bsum[t] : 0;
    __syncthreads();
    for (int d = 1; d < 512; d <<= 1) {
        int v = (t >= d) ? sh[t - d] : 0;
        __syncthreads();
        sh[t] += v;
        __syncthreads();
    }
    if (t < nb) boff[t] = (t == 0) ? 0 : sh[t - 1];
    if (t == 0) offs[n] = E;
}

__global__ __launch_bounds__(256) void blockscan_kernel(
    const int* __restrict__ deg, const int* __restrict__ boff,
    int* __restrict__ offs, int* __restrict__ cursor, int n)
{
    __shared__ int sh[256];
    int t = threadIdx.x;
    int i = blockIdx.x * 256 + t;
    int v = (i < n) ? deg[i] : 0;
    sh[t] = v;
    __syncthreads();
    for (int d = 1; d < 256; d <<= 1) {
        int u = (t >= d) ? sh[t - d] : 0;
        __syncthreads();
        sh[t] += u;
        __syncthreads();
    }
    if (i < n) {
        int ex = boff[blockIdx.x] + sh[t] - v;
        offs[i] = ex; cursor[i] = ex;
    }
}

// XCD-partitioned fill (see R5 notes: keeps csr lines on one XCD's L2)
#define FILL_CHUNK 4096
__global__ __launch_bounds__(256) void fill_part_kernel(
    const int* __restrict__ src, const int* __restrict__ dst,
    int* __restrict__ cursor, int* __restrict__ csr,
    int E, int nPer, int N)
{
    int cls = blockIdx.x & 7;
    int base = (blockIdx.x >> 3) * FILL_CHUNK;
    int lo = cls * nPer;
    int hi = lo + nPer; if (hi > N) hi = N;
    int end = base + FILL_CHUNK; if (end > E) end = E;
    for (int e = base + threadIdx.x; e < end; e += 256) {
        int d = dst[e];
        int s = src[e];
        if (d >= lo && d < hi) {
            int p = atomicAdd(&cursor[d], 1);
            csr[p] = s;
        }
    }
}

// ---------------------------------------------------------------------------
// fp32 -> bf16 bulk convert (8 elems/thread)
// ---------------------------------------------------------------------------
__global__ __launch_bounds__(256) void cvtx_kernel(
    const float* __restrict__ x, ushort* __restrict__ xb, int total8)
{
    int i = blockIdx.x * 256 + threadIdx.x;
    if (i >= total8) return;
    const float* gp = x + (size_t)i * 8;
    float4 v0 = *(const float4*)gp;
    float4 v1 = *(const float4*)(gp + 4);
    short8 pk;
    pk[0] = (short)f2bf(v0.x); pk[1] = (short)f2bf(v0.y);
    pk[2] = (short)f2bf(v0.z); pk[3] = (short)f2bf(v0.w);
    pk[4] = (short)f2bf(v1.x); pk[5] = (short)f2bf(v1.y);
    pk[6] = (short)f2bf(v1.z); pk[7] = (short)f2bf(v1.w);
    *(short8*)(xb + (size_t)i * 8) = pk;
}

// ---------------------------------------------------------------------------
// Weight transpose + fp32->bf16: Wt[c][n][k] = bf16(W[c][k][n])
// ---------------------------------------------------------------------------
__global__ void cvtW_kernel(const float* __restrict__ W, ushort* __restrict__ Wt,
                            int K, int Ncols) {
    __shared__ float tile[32][33];
    int c = blockIdx.z;
    int k0 = blockIdx.x * 32, n0 = blockIdx.y * 32;
    const float* Wc = W + (size_t)c * K * Ncols;
    ushort* Wtc = Wt + (size_t)c * K * Ncols;
    int tx = threadIdx.x & 31, ty = threadIdx.x >> 5;
#pragma unroll
    for (int i = 0; i < 4; ++i) {
        int k = k0 + ty + i * 8;
        tile[ty + i * 8][tx] = Wc[(size_t)k * Ncols + n0 + tx];
    }
    __syncthreads();
#pragma unroll
    for (int i = 0; i < 4; ++i) {
        int n = n0 + ty + i * 8;
        Wtc[(size_t)n * K + k0 + tx] = f2bf(tile[tx][ty + i * 8]);
    }
}

// ---------------------------------------------------------------------------
// Aggregation (bf16 in/out, fp32 accumulate), unroll x4.
// ---------------------------------------------------------------------------
__global__ __launch_bounds__(256) void agg_bf16(
    const ushort* __restrict__ h,
    const int* __restrict__ offs, const int* __restrict__ csr,
    ushort* __restrict__ outb, int n)
{
    int wid = (blockIdx.x * 256 + threadIdx.x) >> 6;
    int lane = threadIdx.x & 63;
    if (wid >= n) return;
    const unsigned int* hb = (const unsigned int*)h;
    unsigned int u = hb[(size_t)wid * 64 + lane];
    float ax = bflo(u), ay = bfhi(u);
    int b = offs[wid], e = offs[wid + 1];
    int j = b;
    for (; j + 4 <= e; j += 4) {
        int s0 = csr[j], s1 = csr[j + 1], s2 = csr[j + 2], s3 = csr[j + 3];
        unsigned int u0 = hb[(size_t)s0 * 64 + lane];
        unsigned int u1 = hb[(size_t)s1 * 64 + lane];
        unsigned int u2 = hb[(size_t)s2 * 64 + lane];
        unsigned int u3 = hb[(size_t)s3 * 64 + lane];
        ax += (bflo(u0) + bflo(u1)) + (bflo(u2) + bflo(u3));
        ay += (bfhi(u0) + bfhi(u1)) + (bfhi(u2) + bfhi(u3));
    }
    for (; j < e; ++j) {
        unsigned int u0 = hb[(size_t)csr[j] * 64 + lane];
        ax += bflo(u0); ay += bfhi(u0);
    }
    unsigned int po = (unsigned int)f2bf(ax) | ((unsigned int)f2bf(ay) << 16);
    ((unsigned int*)outb)[(size_t)wid * 64 + lane] = po;
}

// ---------------------------------------------------------------------------
// Fused GIN-layer MLP (unchanged from R5): Out = relu(relu(relu(A@W0+b0)@W1+b1)@W2+b2)
// ---------------------------------------------------------------------------
__global__ __launch_bounds__(256) void gin_mlp_mfma(
    const ushort* __restrict__ A,
    const ushort* __restrict__ WtL,    // [3][128][128] bf16, n-major
    const float* __restrict__ biasL,   // [3][128]
    ushort* __restrict__ Out,
    int nrows)
{
    __shared__ __align__(16) ushort As[128 * 128];   // 32 KB
    __shared__ __align__(16) ushort Bs[128 * 128];   // 32 KB
    const int t = threadIdx.x;
    const int w = t >> 6, lane = t & 63;
    const int quad = lane >> 4, c15 = lane & 15;
    const int wr = w >> 1, wc = w & 1;
    const int rowbase = blockIdx.x * 128;

#pragma unroll
    for (int i = 0; i < 8; ++i) {
        int lin = (i * 4 + w) * 64 + lane;
        int row = lin >> 4, slot = lin & 15, g = slot ^ (row & 15);
        int grow = rowbase + row;
        if (grow >= nrows) grow = 0;
        const ushort* gp = A + (size_t)grow * 128 + g * 8;
        __builtin_amdgcn_global_load_lds(
            (const __attribute__((address_space(1))) void*)gp,
            (__attribute__((address_space(3))) void*)&As[(i * 4 + w) * 512],
            16, 0, 0);
    }
#pragma unroll
    for (int i = 0; i < 8; ++i) {
        int lin = (i * 4 + w) * 64 + lane;
        int n = lin >> 4, slot = lin & 15, g = slot ^ (n & 15);
        const ushort* gp = WtL + (size_t)n * 128 + g * 8;
        __builtin_amdgcn_global_load_lds(
            (const __attribute__((address_space(1))) void*)gp,
            (__attribute__((address_space(3))) void*)&Bs[(i * 4 + w) * 512],
            16, 0, 0);
    }
    __syncthreads();

    for (int s = 0; s < 3; ++s) {
        f32x4 acc[4][4];
#pragma unroll
        for (int i = 0; i < 4; ++i)
#pragma unroll
            for (int j = 0; j < 4; ++j)
#pragma unroll
                for (int r = 0; r < 4; ++r) acc[i][j][r] = 0.f;

#pragma unroll
        for (int ks = 0; ks < 4; ++ks) {
            short8 af[4], bf[4];
#pragma unroll
            for (int tr = 0; tr < 4; ++tr) {
                int r = wr * 64 + tr * 16 + c15;
                af[tr] = *(const short8*)&As[r * 128 + (((ks * 4 + quad) ^ (r & 15)) * 8)];
            }
#pragma unroll
            for (int tc = 0; tc < 4; ++tc) {
                int n = wc * 64 + tc * 16 + c15;
                bf[tc] = *(const short8*)&Bs[n * 128 + (((ks * 4 + quad) ^ (n & 15)) * 8)];
            }
#pragma unroll
            for (int tr = 0; tr < 4; ++tr)
#pragma unroll
                for (int tc = 0; tc < 4; ++tc)
                    acc[tr][tc] = __builtin_amdgcn_mfma_f32_16x16x32_bf16(
                        af[tr], bf[tc], acc[tr][tc], 0, 0, 0);
        }
        __syncthreads();

        if (s < 2) {
#pragma unroll
            for (int tc = 0; tc < 4; ++tc) {
                int col = wc * 64 + tc * 16 + c15;
                float bv = biasL[s * 128 + col];
#pragma unroll
                for (int tr = 0; tr < 4; ++tr)
#pragma unroll
                    for (int rg = 0; rg < 4; ++rg) {
                        int row = wr * 64 + tr * 16 + quad * 4 + rg;
                        As[row * 128 + (((col >> 3) ^ (row & 15)) * 8) + (col & 7)]
                            = f2bf(fmaxf(acc[tr][tc][rg] + bv, 0.f));
                    }
            }
            const ushort* Wn = WtL + (size_t)(s + 1) * 128 * 128;
#pragma unroll
            for (int i = 0; i < 8; ++i) {
                int lin = (i * 4 + w) * 64 + lane;
                int n = lin >> 4, slot = lin & 15, g = slot ^ (n & 15);
                const ushort* gp = Wn + (size_t)n * 128 + g * 8;
                __builtin_amdgcn_global_load_lds(
                    (const __attribute__((address_space(1))) void*)gp,
                    (__attribute__((address_space(3))) void*)&Bs[(i * 4 + w) * 512],
                    16, 0, 0);
            }
            __syncthreads();
        } else {
#pragma unroll
            for (int tc = 0; tc < 4; ++tc) {
                int col = wc * 64 + tc * 16 + c15;
                float bv = biasL[2 * 128 + col];
#pragma unroll
                for (int tr = 0; tr < 4; ++tr)
#pragma unroll
                    for (int rg = 0; rg < 4; ++rg) {
                        int grow = rowbase + wr * 64 + tr * 16 + quad * 4 + rg;
                        if (grow < nrows)
                            Out[(size_t)grow * 128 + col]
                                = f2bf(fmaxf(acc[tr][tc][rg] + bv, 0.f));
                    }
            }
        }
    }
}

// ---------------------------------------------------------------------------
// Fully fused channel MLP: per block = 64 rows x 1 channel.
//   Phase 1: T1 = relu(concat{xb,h0,h1,h2} @ W1c + b1c)  -> bf16 tile in LDS
//   Phase 2: H2 = relu(T1 @ W2c + b2c)                    (T1 read from LDS)
//   Phase 3: out[r][c] = relu(H2 . w3c + b3c)
// T1 never touches global memory (was 205 MB write + 205 MB read in R5).
// LDS: As 8K + Bs 32K + Ts 32K + red 1K = 73 KB -> 2 blocks/CU.
// Rounding points identical to the unfused version -> absmax unchanged.
// ---------------------------------------------------------------------------
__global__ __launch_bounds__(256, 2) void chan_fused_mfma(
    const ushort* __restrict__ A0, const ushort* __restrict__ A1,
    const ushort* __restrict__ A2, const ushort* __restrict__ A3,
    const ushort* __restrict__ Wt1,    // [NCH*256][512] bf16 n-major
    const float* __restrict__ b1,      // [NCH*256]
    const ushort* __restrict__ Wt2,    // [NCH][256][256] bf16 n-major
    const float* __restrict__ b2,      // [NCH*256]
    const float* __restrict__ w3,      // [NCH*256]
    const float* __restrict__ b3,      // [NCH]
    float* __restrict__ out,           // [N, NCH]
    int N)
{
    __shared__ __align__(16) ushort As[64 * 64];     //  8 KB
    __shared__ __align__(16) ushort Bs[256 * 64];    // 32 KB
    __shared__ __align__(16) ushort Ts[64 * 256];    // 32 KB
    __shared__ float red[64][4];
    const int t = threadIdx.x;
    const int w = t >> 6, lane = t & 63;
    const int quad = lane >> 4, c15 = lane & 15;
    const int rowbase = blockIdx.x * 64;
    const int c = blockIdx.y;
    const ushort* Asrc[4] = {A0, A1, A2, A3};
    const ushort* W1c = Wt1 + (size_t)c * 256 * 512;
    const ushort* W2c = Wt2 + (size_t)c * 256 * 256;

    f32x4 acc[4][4];
#pragma unroll
    for (int i = 0; i < 4; ++i)
#pragma unroll
        for (int j = 0; j < 4; ++j)
#pragma unroll
            for (int r = 0; r < 4; ++r) acc[i][j][r] = 0.f;

    // ---- Phase 1: L1 GEMM, K = 512 over the 4 virtual-concat slices ----
    for (int kc = 0; kc < 512; kc += 64) {
        const ushort* Ab = Asrc[kc >> 7];
        const int within = kc & 127;
#pragma unroll
        for (int i = 0; i < 2; ++i) {
            int lin = (i * 4 + w) * 64 + lane;
            int row = lin >> 3, slot = lin & 7, g = slot ^ (row & 7);
            int grow = rowbase + row;
            if (grow >= N) grow = 0;
            const ushort* gp = Ab + (size_t)grow * 128 + within + g * 8;
            __builtin_amdgcn_global_load_lds(
                (const __attribute__((address_space(1))) void*)gp,
                (__attribute__((address_space(3))) void*)&As[(i * 4 + w) * 512],
                16, 0, 0);
        }
#pragma unroll
        for (int i = 0; i < 8; ++i) {
            int lin = (i * 4 + w) * 64 + lane;
            int n = lin >> 3, slot = lin & 7, g = slot ^ (n & 7);
            const ushort* gp = W1c + (size_t)n * 512 + kc + g * 8;
            __builtin_amdgcn_global_load_lds(
                (const __attribute__((address_space(1))) void*)gp,
                (__attribute__((address_space(3))) void*)&Bs[(i * 4 + w) * 512],
                16, 0, 0);
        }
        __syncthreads();
#pragma unroll
        for (int ks = 0; ks < 2; ++ks) {
            const int K8 = ks * 4;
            short8 af[4], bf[4];
#pragma unroll
            for (int tr = 0; tr < 4; ++tr) {
                int r = tr * 16 + c15;
                af[tr] = *(const short8*)&As[r * 64 + (((K8 + quad) ^ (r & 7)) * 8)];
            }
#pragma unroll
            for (int tc = 0; tc < 4; ++tc) {
                int n = w * 64 + tc * 16 + c15;
                bf[tc] = *(const short8*)&Bs[n * 64 + (((K8 + quad) ^ (n & 7)) * 8)];
            }
#pragma unroll
            for (int tr = 0; tr < 4; ++tr)
#pragma unroll
                for (int tc = 0; tc < 4; ++tc)
                    acc[tr][tc] = __builtin_amdgcn_mfma_f32_16x16x32_bf16(
                        af[tr], bf[tc], acc[tr][tc], 0, 0, 0);
        }
        __syncthreads();
    }

    // ---- T1 tile -> Ts (bf16, 32-granule XOR swizzle per row) ----
#pragma unroll
    for (int tc = 0; tc < 4; ++tc) {
        int col = w * 64 + tc * 16 + c15;
        float bv = b1[c * 256 + col];
#pragma unroll
        for (int tr = 0; tr < 4; ++tr)
#pragma unroll
            for (int rg = 0; rg < 4; ++rg) {
                int row = tr * 16 + quad * 4 + rg;
                Ts[row * 256 + (((col >> 3) ^ (row & 31)) * 8) + (col & 7)]
                    = f2bf(fmaxf(acc[tr][tc][rg] + bv, 0.f));
            }
    }
    __syncthreads();

    // ---- Phase 2: L2 GEMM, K = 256 from Ts ----
#pragma unroll
    for (int i = 0; i < 4; ++i)
#pragma unroll
        for (int j = 0; j < 4; ++j)
#pragma unroll
            for (int r = 0; r < 4; ++r) acc[i][j][r] = 0.f;

    for (int kc = 0; kc < 256; kc += 64) {
#pragma unroll
        for (int i = 0; i < 8; ++i) {
            int lin = (i * 4 + w) * 64 + lane;
            int n = lin >> 3, slot = lin & 7, g = slot ^ (n & 7);
            const ushort* gp = W2c + (size_t)n * 256 + kc + g * 8;
            __builtin_amdgcn_global_load_lds(
                (const __attribute__((address_space(1))) void*)gp,
                (__attribute__((address_space(3))) void*)&Bs[(i * 4 + w) * 512],
                16, 0, 0);
        }
        __syncthreads();
#pragma unroll
        for (int ks = 0; ks < 2; ++ks) {
            short8 af[4], bf[4];
            const int g0 = (kc >> 3) + ks * 4 + quad;
#pragma unroll
            for (int tr = 0; tr < 4; ++tr) {
                int r = tr * 16 + c15;
                af[tr] = *(const short8*)&Ts[r * 256 + ((g0 ^ (r & 31)) * 8)];
            }
#pragma unroll
            for (int tc = 0; tc < 4; ++tc) {
                int n = w * 64 + tc * 16 + c15;
                bf[tc] = *(const short8*)&Bs[n * 64 + ((((ks * 4) + quad) ^ (n & 7)) * 8)];
            }
#pragma unroll
            for (int tr = 0; tr < 4; ++tr)
#pragma unroll
                for (int tc = 0; tc < 4; ++tc)
                    acc[tr][tc] = __builtin_amdgcn_mfma_f32_16x16x32_bf16(
                        af[tr], bf[tc], acc[tr][tc], 0, 0, 0);
        }
        __syncthreads();
    }

    // ---- Phase 3: relu(acc+b2) dot w3 ----
    float b2v[4], w3v[4];
#pragma unroll
    for (int tc = 0; tc < 4; ++tc) {
        int col = w * 64 + tc * 16 + c15;
        b2v[tc] = b2[c * 256 + col];
        w3v[tc] = w3[c * 256 + col];
    }
#pragma unroll
    for (int tr = 0; tr < 4; ++tr)
#pragma unroll
        for (int rg = 0; rg < 4; ++rg) {
            float p = 0.f;
#pragma unroll
            for (int tc = 0; tc < 4; ++tc)
                p += fmaxf(acc[tr][tc][rg] + b2v[tc], 0.f) * w3v[tc];
            p += __shfl_xor(p, 1);
            p += __shfl_xor(p, 2);
            p += __shfl_xor(p, 4);
            p += __shfl_xor(p, 8);
            if (c15 == 0) red[tr * 16 + quad * 4 + rg][w] = p;
        }
    __syncthreads();
    if (t < 64) {
        int grow = rowbase + t;
        if (grow < N) {
            float s = red[t][0] + red[t][1] + red[t][2] + red[t][3] + b3[c];
            out[(size_t)grow * NCH + c] = fmaxf(s, 0.f);
        }
    }
}

// ---------------------------------------------------------------------------
// Launch
// ---------------------------------------------------------------------------
extern "C" void kernel_launch(void* const* d_in, const int* in_sizes, int n_in,
                              void* d_out, int out_size, void* d_ws, size_t ws_size,
                              hipStream_t stream) {
    const float* x        = (const float*)d_in[0];
    const int*   eidx     = (const int*)d_in[1];
    const float* convW    = (const float*)d_in[2];
    const float* convB    = (const float*)d_in[3];
    const float* chanW1   = (const float*)d_in[4];
    const float* chanB1   = (const float*)d_in[5];
    const float* chanW2   = (const float*)d_in[6];
    const float* chanB2   = (const float*)d_in[7];
    const float* chanW3   = (const float*)d_in[8];
    const float* chanB3   = (const float*)d_in[9];
    float* out = (float*)d_out;

    const int N = in_sizes[0] / D;      // 100000
    const int E = in_sizes[1] / 2;      // 1600000
    const int* srcp = eidx;
    const int* dstp = eidx + E;
    const int nb = (N + 255) / 256;     // 391

    char* w = (char*)d_ws;
    auto take = [&](size_t bytes) {
        char* p = w;
        w += (bytes + 255) & ~(size_t)255;
        return p;
    };
    ushort* xb     = (ushort*)take((size_t)N * D * 2);
    ushort* h0     = (ushort*)take((size_t)N * D * 2);
    ushort* h1     = (ushort*)take((size_t)N * D * 2);
    ushort* h2     = (ushort*)take((size_t)N * D * 2);
    int*    deg    = (int*)take((size_t)N * 4);
    int*    offs   = (int*)take((size_t)(N + 1) * 4);
    int*    cursor = (int*)take((size_t)N * 4);
    int*    bsum   = (int*)take((size_t)nb * 4);
    int*    boff   = (int*)take((size_t)nb * 4);
    ushort* Wt1b   = (ushort*)take((size_t)NCH * 256 * 512 * 2);
    ushort* Wt2b   = (ushort*)take((size_t)NCH * 256 * 256 * 2);
    ushort* WtC    = (ushort*)take((size_t)NLAYER * 3 * D * D * 2);

    size_t used = (size_t)(w - (char*)d_ws);
    if (used > ws_size) return;
    size_t rem = ws_size - used;
    size_t need_gin = (((size_t)E * 4 + 255) & ~(size_t)255) + (size_t)N * D * 2;
    if (rem < need_gin) return;

    int*    csr = (int*)w;
    ushort* a   = (ushort*)(w + (((size_t)E * 4 + 255) & ~(size_t)255));

    // --- CSR build (parallel scan + XCD-partitioned fill) ---
    hipMemsetAsync(deg, 0, (size_t)N * 4, stream);
    hist_kernel<<<(E + 255) / 256, 256, 0, stream>>>(dstp, deg, E);
    blocksum_kernel<<<nb, 256, 0, stream>>>(deg, bsum, N);
    scanblk_kernel<<<1, 512, 0, stream>>>(bsum, boff, nb, offs, N, E);
    blockscan_kernel<<<nb, 256, 0, stream>>>(deg, boff, offs, cursor, N);
    {
        int nchunks = (E + FILL_CHUNK - 1) / FILL_CHUNK;
        int nPer = (N + 7) / 8;
        fill_part_kernel<<<nchunks * 8, 256, 0, stream>>>(
            srcp, dstp, cursor, csr, E, nPer, N);
    }

    // --- converts (independent) ---
    cvtx_kernel<<<(N * 16 + 255) / 256, 256, 0, stream>>>(x, xb, N * 16);
    cvtW_kernel<<<dim3(512 / 32, 256 / 32, NCH), 256, 0, stream>>>(chanW1, Wt1b, 512, 256);
    cvtW_kernel<<<dim3(256 / 32, 256 / 32, NCH), 256, 0, stream>>>(chanW2, Wt2b, 256, 256);
    cvtW_kernel<<<dim3(D / 32, D / 32, NLAYER * 3), 256, 0, stream>>>(convW, WtC, D, D);

    const int rowtiles = (N + 127) / 128;
    const int aggblocks = (N * 64 + 255) / 256;

    // --- GIN layers: agg + fused 3-linear MLP per layer ---
    ushort* hbuf[NLAYER] = {h0, h1, h2};
    const ushort* prev = xb;
    for (int l = 0; l < NLAYER; ++l) {
        agg_bf16<<<aggblocks, 256, 0, stream>>>(prev, offs, csr, a, N);
        gin_mlp_mfma<<<rowtiles, 256, 0, stream>>>(
            a, WtC + (size_t)l * 3 * D * D, convB + (size_t)l * 3 * D, hbuf[l], N);
        prev = hbuf[l];
    }

    // --- channel MLPs: fully fused (T1 lives in LDS only) ---
    const int rt64 = (N + 63) / 64;
    chan_fused_mfma<<<dim3(rt64, NCH), 256, 0, stream>>>(
        xb, h0, h1, h2,
        Wt1b, chanB1, Wt2b, chanB2, chanW3, chanB3,
        out, N);
}